// Round 17
// baseline (184.118 us; speedup 1.0000x reference)
//
#include <hip/hip_runtime.h>
#include <hip/hip_bf16.h>
#include <cstdint>

#define T_SEQ 2048
#define DIM   1024
#define NHEAD 16
#define NKVH  8
#define HDIM  64
#define QKVN  3584   // 2048 (q) + 1024 (k) + 512 (v)

static constexpr float LAMBDA_INIT_F = 0.3555090675909693f;
static constexpr float ONE_MINUS_LI  = 0.6444909324090307f;
static constexpr float QSCALE_EXP2   = 0.1803368801111144f;  // 0.125 * log2(e)

typedef __bf16 bf16x8 __attribute__((ext_vector_type(8)));
typedef float  f32x4  __attribute__((ext_vector_type(4)));

static __device__ __forceinline__ ushort f2bf(float f) {
  union { float f; uint32_t u; } x; x.f = f;
  uint32_t u = x.u;
  uint32_t r = (u + 0x7fffu + ((u >> 16) & 1u)) >> 16;
  return (ushort)r;
}
static __device__ __forceinline__ float bf2f(ushort u) {
  union { uint32_t u; float f; } x; x.u = ((uint32_t)u) << 16; return x.f;
}
static __device__ __forceinline__ f32x4 zero4() {
  f32x4 z = {0.f, 0.f, 0.f, 0.f}; return z;
}
// Fragment-interleaved layout: within each 32-element k-block, quad q (=k>>2) is
// stored at offset ((q&3)<<3) + ((q>>2)<<2). A lane's 8 frag elements
// {4g..4g+3, 16+4g..19+4g} land contiguously at [8g..8g+7] -> one 16B load.
static __device__ __forceinline__ bf16x8 ldfrag128(const ushort* p) {
  union { bf16x8 v; uint4 u; } r;
  r.u = *(const uint4*)p;
  return r.v;
}
// async global->LDS, 16B per lane; lds dest = base + lane*16 (wave-uniform base)
static __device__ __forceinline__ void gll16(const ushort* g, ushort* l) {
  __builtin_amdgcn_global_load_lds(
      (const __attribute__((address_space(1))) uint32_t*)g,
      (__attribute__((address_space(3))) uint32_t*)l, 16, 0, 0);
}

// ---------------- fused fp32->bf16 conversion, frag-interleaved output -------------
__global__ void cvt_all(const float* __restrict__ x,  const float* __restrict__ wq,
                        const float* __restrict__ wk, const float* __restrict__ wv,
                        const float* __restrict__ wo,
                        ushort* __restrict__ xb, ushort* __restrict__ Wb,
                        ushort* __restrict__ Wob) {
  int g = (blockIdx.x * 256 + threadIdx.x) * 4;   // < 6815744, 4-aligned
  float4 v; ushort* dst; int j;
  if (g < 2097152) {
    v = *(const float4*)(x + g); dst = xb; j = g;
  } else if (g < 5767168) {
    j = g - 2097152;
    const float* src = (j < 2097152) ? (wq + j)
                     : (j < 3145728) ? (wk + (j - 2097152))
                                     : (wv + (j - 3145728));
    v = *(const float4*)src; dst = Wb;
  } else {
    j = g - 5767168;
    v = *(const float4*)(wo + j); dst = Wob;
  }
  int q = (j & 31) >> 2;                         // quad within 32-block
  int jp = (j & ~31) + ((q & 3) << 3) + ((q >> 2) << 2);
  ushort4 o4;
  o4.x = f2bf(v.x); o4.y = f2bf(v.y); o4.z = f2bf(v.z); o4.w = f2bf(v.w);
  *(ushort4*)(dst + jp) = o4;
}

__global__ void lam_kernel(const float* __restrict__ lq1, const float* __restrict__ lk1,
                           const float* __restrict__ lq2, const float* __restrict__ lk2,
                           float* __restrict__ lam) {
  int lane = threadIdx.x;  // 64 threads
  float p1 = lq1[lane] * lk1[lane];
  float p2 = lq2[lane] * lk2[lane];
  #pragma unroll
  for (int off = 32; off >= 1; off >>= 1) {
    p1 += __shfl_down(p1, off);
    p2 += __shfl_down(p2, off);
  }
  if (lane == 0) *lam = expf(p1) - expf(p2) + LAMBDA_INIT_F;
}

// ---------------- GEMM (m97 + T1 swizzle), frag-interleaved inputs, b128 reads -----
template<int BF16OUT>
__global__ __launch_bounds__(256) void gemm_bt(const ushort* __restrict__ A,
                                               const ushort* __restrict__ W,
                                               void* __restrict__ Cout,
                                               int M, int N, int K) {
  __shared__ __align__(16) ushort As[128 * 32];
  __shared__ __align__(16) ushort Ws[128 * 32];
  const int tid  = threadIdx.x;
  const int lane = tid & 63;
  const int w    = tid >> 6;
  const int wr   = w >> 1, wc = w & 1;
  const int nwg = gridDim.x * gridDim.y;
  int id  = blockIdx.x * gridDim.y + blockIdx.y;
  int sw  = (id & 7) * (nwg >> 3) + (id >> 3);
  const int bm = (sw % gridDim.y) * 128;
  const int bn = (sw / gridDim.y) * 128;
  const int fr = lane & 15;
  const int fg = (lane >> 4) * 4;
  const int g8 = (lane >> 4) * 8;

  f32x4 acc[4][4];
  #pragma unroll
  for (int m = 0; m < 4; ++m)
    #pragma unroll
    for (int n = 0; n < 4; ++n) acc[m][n] = zero4();

  const int col  = (lane & 3) * 8;
  const int row0 = w * 16 + (lane >> 2);
  const int row1 = row0 + 64;
  const ushort* ga0 = A + (size_t)(bm + row0) * K + col;
  const ushort* ga1 = A + (size_t)(bm + row1) * K + col;
  const ushort* gw0 = W + (size_t)(bn + row0) * K + col;
  const ushort* gw1 = W + (size_t)(bn + row1) * K + col;
  ushort* la0 = As + (w * 512);
  ushort* la1 = As + (w * 512) + 2048;
  ushort* lw0 = Ws + (w * 512);
  ushort* lw1 = Ws + (w * 512) + 2048;

  for (int k0 = 0; k0 < K; k0 += 32) {
    gll16(ga0 + k0, la0);
    gll16(ga1 + k0, la1);
    gll16(gw0 + k0, lw0);
    gll16(gw1 + k0, lw1);
    __syncthreads();
    bf16x8 af[4], bfr[4];
    #pragma unroll
    for (int m = 0; m < 4; ++m) af[m]  = ldfrag128(&As[(wr*64 + m*16 + fr) * 32 + g8]);
    #pragma unroll
    for (int n = 0; n < 4; ++n) bfr[n] = ldfrag128(&Ws[(wc*64 + n*16 + fr) * 32 + g8]);
    #pragma unroll
    for (int m = 0; m < 4; ++m)
      #pragma unroll
      for (int n = 0; n < 4; ++n)
        acc[m][n] = __builtin_amdgcn_mfma_f32_16x16x32_bf16(af[m], bfr[n], acc[m][n], 0, 0, 0);
    __syncthreads();
  }

  #pragma unroll
  for (int m = 0; m < 4; ++m)
    #pragma unroll
    for (int n = 0; n < 4; ++n)
      #pragma unroll
      for (int i = 0; i < 4; ++i) {
        int row = bm + wr*64 + m*16 + fg + i;
        int colg = bn + wc*64 + n*16 + fr;
        float v = acc[m][n][i];
        if (BF16OUT) ((ushort*)Cout)[(size_t)row * N + colg] = f2bf(v);
        else         ((float*)Cout)[(size_t)row * N + colg]  = v;
      }
}

// ---------------- fused RoPE Q, RoPE K, pack V -> frag-interleaved layouts ---------
// Q scaled by 0.125*log2(e). Qr/Kr: d-dim permuted per 32-block; Vt: t-dim permuted.
__global__ void reorg(const ushort* __restrict__ QKV, ushort* __restrict__ Qr,
                      ushort* __restrict__ Kr, ushort* __restrict__ Vt,
                      const float* __restrict__ fc, const float* __restrict__ fs) {
  int idx = blockIdx.x * 256 + threadIdx.x;   // < 917504
  if (idx < 786432) {
    // RoPE, 4 interleaved pairs = 8 consecutive logical d per thread
    int nheads, col_off; ushort* dst; float scale; int id;
    if (idx < 524288) { id = idx * 4; nheads = NHEAD; col_off = 0; dst = Qr; scale = QSCALE_EXP2; }
    else { id = (idx - 524288) * 4; nheads = NKVH; col_off = 2048; dst = Kr; scale = 1.0f; }
    int per_t = nheads * 64;
    int t  = id / per_t;
    int r  = id - t * per_t;
    int hh = r >> 6;
    int c2 = (r >> 5) & 1;
    int j  = r & 31;                      // multiple of 4; logical d0 = 2j
    int cl = col_off + hh * 128 + c2 * 64 + 2 * j;
    uint4 raw = *(const uint4*)(QKV + (size_t)t * QKVN + cl);
    const ushort* rp = (const ushort*)&raw;
    float c4[4], s4[4];
    *(float4*)c4 = *(const float4*)(fc + t * 32 + j);
    *(float4*)s4 = *(const float4*)(fs + t * 32 + j);
    ushort outv[8];
    #pragma unroll
    for (int p = 0; p < 4; ++p) {
      float rv = bf2f(rp[2*p]), iv = bf2f(rp[2*p + 1]);
      outv[2*p]     = f2bf((rv * c4[p] - iv * s4[p]) * scale);
      outv[2*p + 1] = f2bf((rv * s4[p] + iv * c4[p]) * scale);
    }
    int d0 = 2 * j;
    int o  = d0 & 31;                     // 0,8,16,24
    int q0 = o >> 2;                      // 0,2,4,6
    int s0 = ((q0 & 3) << 3) + ((q0 >> 2) << 2);
    int s1 = (((q0+1) & 3) << 3) + (((q0+1) >> 2) << 2);
    size_t ob = ((size_t)(c2 * nheads + hh) * T_SEQ + t) * HDIM + (d0 & ~31);
    *(uint2*)(dst + ob + s0) = *(const uint2*)(outv);
    *(uint2*)(dst + ob + s1) = *(const uint2*)(outv + 4);
  } else {
    // V transpose: 8 t-consecutive elems, t-permuted within 32-blocks
    int id = (idx - 786432) * 8;           // < 1048576
    int t = id & (T_SEQ - 1);              // multiple of 8
    int rest = id >> 11;                   // kh*64 + d
    ushort outv[8];
    #pragma unroll
    for (int p = 0; p < 8; ++p) outv[p] = QKV[(size_t)(t + p) * QKVN + 3072 + rest];
    int o  = t & 31;
    int q0 = o >> 2;
    int s0 = ((q0 & 3) << 3) + ((q0 >> 2) << 2);
    int s1 = (((q0+1) & 3) << 3) + (((q0+1) >> 2) << 2);
    size_t ob = (size_t)rest * T_SEQ + (t & ~31);
    *(uint2*)(Vt + ob + s0) = *(const uint2*)(outv);
    *(uint2*)(Vt + ob + s1) = *(const uint2*)(outv + 4);
  }
}

// ---------------- flash attention: barrier-free + split-K on heavy half ------------
// 768 blocks, XCD affinity: kh = bx & 7 (one kh group per XCD). inner = bx>>3 in
// [0,96): h = 2*kh + (inner&1); s = inner>>1 in [0,48):
//   s < 32: SPLIT block, qb = 31-(s>>1) in [16,31], chunk c = s&1:
//           c=0 -> tiles [0,(qb+1)/2), c=1 -> [(qb+1)/2, qb+1]
//           epilogue writes unnormalized fp32 O + (m,l) partials (rows 1024..2047).
//   s >= 32: UNSPLIT, qb = 47-s in [0,15]: LDS stream-combine + direct Yf write.
// Wave w: stream st = w>>1, q-half qh = w&1; per wave o_/m_/l_ indexed by 16-row
// chunk qs in {0,1}. K/V frags direct from L2; rotated K prefetch; setprio.
__global__ __launch_bounds__(256) void attn_kernel(const ushort* __restrict__ Qr,
                                                   const ushort* __restrict__ Kr,
                                                   const ushort* __restrict__ Vt,
                                                   const float* __restrict__ lamp,
                                                   float* __restrict__ Yf,
                                                   float* __restrict__ part,
                                                   float* __restrict__ Opart,
                                                   float* __restrict__ Ml) {
  const int bx = blockIdx.x;          // 0..767
  const int kh = bx & 7;              // XCD affinity
  const int inner = bx >> 3;          // 0..95
  const int h  = kh * 2 + (inner & 1);
  const int s  = inner >> 1;          // 0..47, heavy-first
  int qb, kt0, kt1, c;
  if (s < 32) {
    qb = 31 - (s >> 1); c = s & 1;
    int sp = (qb + 1) >> 1;
    kt0 = c ? sp : 0;
    kt1 = c ? (qb + 1) : sp;
  } else {
    qb = 47 - s; c = -1;
    kt0 = 0; kt1 = qb + 1;
  }
  const int tid = threadIdx.x;
  const int lane = tid & 63;
  const int w   = tid >> 6;
  const int st  = w >> 1;             // stream 0/1
  const int qh  = w & 1;              // q-half 0/1
  const int fr  = lane & 15;
  const int fg  = (lane >> 4) * 4;
  const int g8  = (lane >> 4) * 8;

  __shared__ float ob[64 * 64];       // epilogue O2 exchange (16 KB, unsplit only)
  __shared__ float sb[8];

  // Q fragments for this wave's stream, two 16-q chunks (frag-interleaved global)
  bf16x8 qf[2][2];                     // [qs][ks]
  #pragma unroll
  for (int qs = 0; qs < 2; ++qs) {
    const int row = qb * 64 + qh * 32 + qs * 16 + fr;
    const ushort* qp = Qr + ((size_t)(st * NHEAD + h) * T_SEQ + row) * HDIM;
    qf[qs][0] = ldfrag128(qp + g8);
    qf[qs][1] = ldfrag128(qp + 32 + g8);
  }

  float m_[2] = {-__builtin_inff(), -__builtin_inff()};
  float l_[2] = {0.f, 0.f};
  f32x4 o_[2][4];
  #pragma unroll
  for (int qs = 0; qs < 2; ++qs)
    #pragma unroll
    for (int dn = 0; dn < 4; ++dn) o_[qs][dn] = zero4();

  // per-lane fragment base pointers (row picked by fr, 16B chunk by g8)
  const ushort* Kbase = Kr + ((size_t)(st * NKVH + kh) * T_SEQ + fr) * HDIM + g8;
  const ushort* Vbase = Vt + ((size_t)(kh * 64 + fr) * T_SEQ) + g8;

  // K fragments (single buffer, reloaded mid-tile after QK consumes them)
  bf16x8 kf[4][2], vf[4][2];
  #pragma unroll
  for (int n = 0; n < 4; ++n) {
    const ushort* kp = Kbase + (size_t)(kt0 * 64 + n * 16) * HDIM;
    kf[n][0] = ldfrag128(kp);
    kf[n][1] = ldfrag128(kp + 32);
  }

  for (int kt = kt0; kt < kt1; ++kt) {
    const int kvb = kt * 64;

    // V fragments for this tile (needed only after softmax -> self-hiding)
    #pragma unroll
    for (int dn = 0; dn < 4; ++dn) {
      const ushort* vp = Vbase + (size_t)(dn * 16) * T_SEQ + kvb;
      vf[dn][0] = ldfrag128(vp);
      vf[dn][1] = ldfrag128(vp + 32);
    }

    // S^T: mfma(K rows, Q cols); one K frag serves both q-chunks
    float sv[2][4][4];
    __builtin_amdgcn_s_setprio(1);
    #pragma unroll
    for (int n = 0; n < 4; ++n) {
      f32x4 a0 = zero4(), a1 = zero4();
      #pragma unroll
      for (int ks = 0; ks < 2; ++ks) {
        a0 = __builtin_amdgcn_mfma_f32_16x16x32_bf16(kf[n][ks], qf[0][ks], a0, 0, 0, 0);
        a1 = __builtin_amdgcn_mfma_f32_16x16x32_bf16(kf[n][ks], qf[1][ks], a1, 0, 0, 0);
      }
      #pragma unroll
      for (int i = 0; i < 4; ++i) { sv[0][n][i] = a0[i]; sv[1][n][i] = a1[i]; }
    }
    __builtin_amdgcn_s_setprio(0);

    // kf is dead now -- reload it for tile kt+1; latency hides under softmax+PV
    if (kt + 1 < kt1) {
      #pragma unroll
      for (int n = 0; n < 4; ++n) {
        const ushort* kp = Kbase + (size_t)(kvb + 64 + n * 16) * HDIM;
        kf[n][0] = ldfrag128(kp);
        kf[n][1] = ldfrag128(kp + 32);
      }
    }

    if (kt == qb) {                  // causal mask on diagonal tile
      #pragma unroll
      for (int qs = 0; qs < 2; ++qs) {
        const int qloc = qh*32 + qs*16 + fr;
        #pragma unroll
        for (int n = 0; n < 4; ++n)
          #pragma unroll
          for (int i = 0; i < 4; ++i)
            if (n*16 + fg + i > qloc) sv[qs][n][i] = -__builtin_inff();
      }
    }

    bf16x8 pa[2][2];
    #pragma unroll
    for (int qs = 0; qs < 2; ++qs) {
      float rm = -__builtin_inff();
      #pragma unroll
      for (int n = 0; n < 4; ++n)
        #pragma unroll
        for (int i = 0; i < 4; ++i) rm = fmaxf(rm, sv[qs][n][i]);
      rm = fmaxf(rm, __shfl_xor(rm, 16));
      rm = fmaxf(rm, __shfl_xor(rm, 32));
      if (!__all(rm <= m_[qs] + 8.f)) {   // defer-max (exp2 domain, THR=8)
        float mnew = fmaxf(m_[qs], rm);
        float sc = __builtin_amdgcn_exp2f(m_[qs] - mnew);
        m_[qs] = mnew;
        l_[qs] *= sc;
        float scs[4];
        #pragma unroll
        for (int i = 0; i < 4; ++i) scs[i] = __shfl(sc, fg + i);
        #pragma unroll
        for (int dn = 0; dn < 4; ++dn)
          #pragma unroll
          for (int i = 0; i < 4; ++i) o_[qs][dn][i] *= scs[i];
      }
      float rs = 0.f;
      #pragma unroll
      for (int n = 0; n < 4; ++n)
        #pragma unroll
        for (int i = 0; i < 4; ++i) {
          float p = __builtin_amdgcn_exp2f(sv[qs][n][i] - m_[qs]);
          sv[qs][n][i] = p; rs += p;
        }
      rs += __shfl_xor(rs, 16);
      rs += __shfl_xor(rs, 32);
      l_[qs] += rs;
      #pragma unroll
      for (int ks = 0; ks < 2; ++ks)
        #pragma unroll
        for (int n2 = 0; n2 < 2; ++n2)
          #pragma unroll
          for (int i = 0; i < 4; ++i)
            pa[qs][ks][n2*4 + i] = (__bf16)sv[qs][2*ks + n2][i];
    }

    // O += P @ V; one V frag serves both q-chunks
    __builtin_amdgcn_s_setprio(1);
    #pragma unroll
    for (int ks = 0; ks < 2; ++ks)
      #pragma unroll
      for (int dn = 0; dn < 4; ++dn) {
        o_[0][dn] = __builtin_amdgcn_mfma_f32_16x16x32_bf16(pa[0][ks], vf[dn][ks], o_[0][dn], 0, 0, 0);
        o_[1][dn] = __builtin_amdgcn_mfma_f32_16x16x32_bf16(pa[1][ks], vf[dn][ks], o_[1][dn], 0, 0, 0);
      }
    __builtin_amdgcn_s_setprio(0);
  }

  if (s < 32) {
    // SPLIT epilogue: wave covers stream st, rows qh*32 + qs*16 (qs = chunk index)
    const int plane = (c*2 + st)*16 + h;
    #pragma unroll
    for (int qs = 0; qs < 2; ++qs)
      #pragma unroll
      for (int dn = 0; dn < 4; ++dn)
        #pragma unroll
        for (int i = 0; i < 4; ++i) {
          int rp = qb*64 + qh*32 + qs*16 + fg + i - 1024;   // qb>=16 -> [0,1024)
          Opart[((size_t)plane*1024 + rp)*64 + dn*16 + fr] = o_[qs][dn][i];
        }
    if (lane < 16) {
      #pragma unroll
      for (int qs = 0; qs < 2; ++qs) {
        int rp = qb*64 + qh*32 + qs*16 + fr - 1024;
        Ml[(size_t)plane*1024 + rp]         = m_[qs];
        Ml[65536 + (size_t)plane*1024 + rp] = l_[qs];
      }
    }
    return;
  }

  // UNSPLIT epilogue: normalize; exchange stream-1 O via LDS; combine + Yf + LN
  float iq[2][4];
  #pragma unroll
  for (int qs = 0; qs < 2; ++qs) {
    float inv = __builtin_amdgcn_rcpf(l_[qs]);
    #pragma unroll
    for (int i = 0; i < 4; ++i) iq[qs][i] = __shfl(inv, fg + i);
  }
  __syncthreads();
  if (st == 1) {
    #pragma unroll
    for (int qs = 0; qs < 2; ++qs)
      #pragma unroll
      for (int dn = 0; dn < 4; ++dn)
        #pragma unroll
        for (int i = 0; i < 4; ++i)
          ob[(qh*32 + qs*16 + fg + i)*64 + dn*16 + fr] = o_[qs][dn][i] * iq[qs][i];
  }
  __syncthreads();
  if (st == 0) {
    const float lam = *lamp;
    float sa = 0.f, sa2 = 0.f;
    #pragma unroll
    for (int qs = 0; qs < 2; ++qs)
      #pragma unroll
      for (int dn = 0; dn < 4; ++dn)
        #pragma unroll
        for (int i = 0; i < 4; ++i) {
          int r64 = qh*32 + qs*16 + fg + i;
          int d   = dn*16 + fr;
          float v = o_[qs][dn][i] * iq[qs][i] - lam * ob[r64*64 + d];
          Yf[(size_t)(qb*64 + r64) * DIM + h*64 + d] = v;
          sa += v; sa2 += v * v;
        }
    #pragma unroll
    for (int off = 1; off <= 32; off <<= 1) {
      sa  += __shfl_xor(sa, off);
      sa2 += __shfl_xor(sa2, off);
    }
    if (lane == 0) { sb[w] = sa; sb[4 + w] = sa2; }   // w in {0,1}
  }
  __syncthreads();
  if (tid == 0) {
    part[qb*16 + h]       = sb[0] + sb[1];
    part[512 + qb*16 + h] = sb[4] + sb[5];
  }
}

// ---------------- merge split chunks (rows 1024..2047) + combine + LN partials -----
__global__ __launch_bounds__(256) void merge_stats(const float* __restrict__ Opart,
                                                   const float* __restrict__ Ml,
                                                   const float* __restrict__ lamp,
                                                   float* __restrict__ Yf,
                                                   float* __restrict__ part) {
  const int h = blockIdx.x & 15, sl = blockIdx.x >> 4;   // 16 slices x 64 rows
  const float lam = *lamp;
  float s = 0.f, s2 = 0.f;
  for (int e = threadIdx.x; e < 1024; e += 256) {   // 64 rows x 16 float4
    int rp = sl * 64 + (e >> 4);                    // 0..1023
    int d4 = (e & 15) * 4;
    float o[2][4];
    #pragma unroll
    for (int st = 0; st < 2; ++st) {
      int p0 = st*16 + h;            // chunk 0
      int p1 = (2 + st)*16 + h;      // chunk 1
      float m0 = Ml[(size_t)p0*1024 + rp], l0 = Ml[65536 + (size_t)p0*1024 + rp];
      float m1 = Ml[(size_t)p1*1024 + rp], l1 = Ml[65536 + (size_t)p1*1024 + rp];
      float M  = fmaxf(m0, m1);
      float w0 = __builtin_amdgcn_exp2f(m0 - M);
      float w1 = __builtin_amdgcn_exp2f(m1 - M);
      float inv = 1.f / (l0 * w0 + l1 * w1);
      float4 a = *(const float4*)(Opart + ((size_t)p0*1024 + rp)*64 + d4);
      float4 b = *(const float4*)(Opart + ((size_t)p1*1024 + rp)*64 + d4);
      o[st][0] = (a.x * w0 + b.x * w1) * inv;
      o[st][1] = (a.y * w0 + b.y * w1) * inv;
      o[st][2] = (a.z * w0 + b.z * w1) * inv;
      o[st][3] = (a.w * w0 + b.w * w1) * inv;
    }
    float4 v;
    v.x = o[0][0] - lam * o[1][0];
    v.y = o[0][1] - lam * o[1][1];
    v.z = o[0][2] - lam * o[1][2];
    v.w = o[0][3] - lam * o[1][3];
    s  += v.x + v.y + v.z + v.w;
    s2 += v.x*v.x + v.y*v.y + v.z*v.z + v.w*v.w;
    *(float4*)(Yf + (size_t)(1024 + rp) * DIM + h * 64 + d4) = v;
  }
  #pragma unroll
  for (int off = 32; off >= 1; off >>= 1) { s += __shfl_down(s, off); s2 += __shfl_down(s2, off); }
  __shared__ float sb[8];
  int wv = threadIdx.x >> 6, lane = threadIdx.x & 63;
  if (lane == 0) { sb[wv] = s; sb[4 + wv] = s2; }
  __syncthreads();
  if (threadIdx.x == 0) {
    part[256 + blockIdx.x]       = sb[0] + sb[1] + sb[2] + sb[3];
    part[512 + 256 + blockIdx.x] = sb[4] + sb[5] + sb[6] + sb[7];
  }
}

// ---------------- finalize per-head stats ----------------
__global__ void stats_final(const float* __restrict__ part, float* __restrict__ stat) {
  int hh = threadIdx.x;
  if (hh < 16) {
    float S = 0.f, S2 = 0.f;
    #pragma unroll
    for (int j = 0; j < 16; ++j) {
      S  += part[j*16 + hh] + part[256 + j*16 + hh];
      S2 += part[512 + j*16 + hh] + part[512 + 256 + j*16 + hh];
    }
    const float N = (float)(T_SEQ * HDIM);
    float mean = S / N;
    float var  = S2 / N - mean * mean;
    stat[hh]      = mean;
    stat[16 + hh] = rsqrtf(var + 1e-5f);
  }
}

// Yb written frag-interleaved (gemm2 expects it)
__global__ void norm_cvt(const float* __restrict__ Y, const float* __restrict__ stats,
                         ushort* __restrict__ Yb) {
  int idx = (blockIdx.x * 256 + threadIdx.x) * 4;   // < T*DIM, 4-aligned
  int col = idx & (DIM - 1);
  int h = col >> 6;
  float mean = stats[h], isd = stats[16 + h] * ONE_MINUS_LI;
  float4 v = *(const float4*)(Y + idx);
  ushort4 o4;
  o4.x = f2bf((v.x - mean) * isd);
  o4.y = f2bf((v.y - mean) * isd);
  o4.z = f2bf((v.z - mean) * isd);
  o4.w = f2bf((v.w - mean) * isd);
  int q = (col & 31) >> 2;
  int idxp = (idx & ~31) + ((q & 3) << 3) + ((q >> 2) << 2);
  *(ushort4*)(Yb + idxp) = o4;
}

// ---------------- launch ----------------
extern "C" void kernel_launch(void* const* d_in, const int* in_sizes, int n_in,
                              void* d_out, int out_size, void* d_ws, size_t ws_size,
                              hipStream_t stream) {
  const float* x   = (const float*)d_in[0];
  const float* fc  = (const float*)d_in[1];
  const float* fs  = (const float*)d_in[2];
  const float* wq  = (const float*)d_in[3];
  const float* wk  = (const float*)d_in[4];
  const float* wv  = (const float*)d_in[5];
  const float* wo  = (const float*)d_in[6];
  const float* lq1 = (const float*)d_in[7];
  const float* lk1 = (const float*)d_in[8];
  const float* lq2 = (const float*)d_in[9];
  const float* lk2 = (const float*)d_in[10];
  float* out = (float*)d_out;

  char* ws = (char*)d_ws;
  // Liveness:
  //  phase1 (cvt/gemm1/reorg): Wob | xb | Wb | QKVb | Qr Kr Vt
  //  phase2 (attn):   Wob | Opart+Ml+Yf (over dead xb/Wb/QKVb) | Qr Kr Vt
  //  phase3 (merge..gemm2): Wob | Opart Ml Yf | Yb
  const size_t OFF_WOB  = 0;                 // 2 MB, live till end
  const size_t OFF_XB   = 2097152;           // 4 MB, dead after gemm1
  const size_t OFF_WB   = 6291456;           // 7 MB, dead after gemm1
  const size_t OFF_QKV  = 13631488;          // 14.68 MB, dead after reorg
  const size_t OFF_QR   = 28311552;          // 8 MB, live through attn
  const size_t OFF_KR   = 36700160;          // 4 MB, live through attn
  const size_t OFF_VT   = 40894464;          // 2 MB, live through attn
  const size_t OFF_OP   = 2097152;           // 16.78 MB fp32 O partials
  const size_t OFF_ML   = 18874368;          // 512 KB fp32 m+l
  const size_t OFF_Y    = 19398656;          // 8 MB fp32 Y  [ends 27787264 < OFF_QR]
  const size_t OFF_YB   = 42991616;          // 4 MB
  const size_t OFF_ST   = 47185920;          // stats + lam + partials

  ushort* xb   = (ushort*)(ws + OFF_XB);
  ushort* Wb   = (ushort*)(ws + OFF_WB);
  ushort* Wob  = (ushort*)(ws + OFF_WOB);
  ushort* QKVb = (ushort*)(ws + OFF_QKV);
  ushort* Qr   = (ushort*)(ws + OFF_QR);
  ushort* Kr   = (ushort*)(ws + OFF_KR);
  ushort* Vt   = (ushort*)(ws + OFF_VT);
  float*  Opart= (float*)(ws + OFF_OP);
  float*  Ml   = (float*)(ws + OFF_ML);
  float*  Yf   = (float*)(ws + OFF_Y);
  ushort* Yb   = (ushort*)(ws + OFF_YB);
  float*  stat = (float*)(ws + OFF_ST);
  float*  lamp = stat + 32;
  float*  part = stat + 64;                  // 1024 floats

  cvt_all<<<6656, 256, 0, stream>>>(x, wq, wk, wv, wo, xb, Wb, Wob);
  lam_kernel<<<1, 64, 0, stream>>>(lq1, lk1, lq2, lk2, lamp);

  gemm_bt<1><<<dim3(QKVN/128, T_SEQ/128), 256, 0, stream>>>(xb, Wb, QKVb, T_SEQ, QKVN, DIM);

  reorg<<<3584, 256, 0, stream>>>(QKVb, Qr, Kr, Vt, fc, fs);

  attn_kernel<<<768, 256, 0, stream>>>(Qr, Kr, Vt, lamp, Yf, part, Opart, Ml);

  merge_stats<<<256, 256, 0, stream>>>(Opart, Ml, lamp, Yf, part);
  stats_final<<<1, 64, 0, stream>>>(part, stat);
  norm_cvt<<<2048, 256, 0, stream>>>(Yf, stat, Yb);

  gemm_bt<0><<<dim3(DIM/128, T_SEQ/128), 256, 0, stream>>>(Yb, Wob, out, T_SEQ, DIM, DIM);
}

// Round 18
// 147.956 us; speedup vs baseline: 1.2444x; 1.2444x over previous
//
#include <hip/hip_runtime.h>
#include <hip/hip_bf16.h>
#include <cstdint>

#define T_SEQ 2048
#define DIM   1024
#define NHEAD 16
#define NKVH  8
#define HDIM  64
#define QKVN  3584   // 2048 (q) + 1024 (k) + 512 (v)

static constexpr float LAMBDA_INIT_F = 0.3555090675909693f;
static constexpr float ONE_MINUS_LI  = 0.6444909324090307f;
static constexpr float QSCALE_EXP2   = 0.1803368801111144f;  // 0.125 * log2(e)

typedef __bf16 bf16x8 __attribute__((ext_vector_type(8)));
typedef float  f32x4  __attribute__((ext_vector_type(4)));

static __device__ __forceinline__ ushort f2bf(float f) {
  union { float f; uint32_t u; } x; x.f = f;
  uint32_t u = x.u;
  uint32_t r = (u + 0x7fffu + ((u >> 16) & 1u)) >> 16;
  return (ushort)r;
}
static __device__ __forceinline__ float bf2f(ushort u) {
  union { uint32_t u; float f; } x; x.u = ((uint32_t)u) << 16; return x.f;
}
static __device__ __forceinline__ f32x4 zero4() {
  f32x4 z = {0.f, 0.f, 0.f, 0.f}; return z;
}
// Fragment-interleaved layout: within each 32-element k-block, quad q (=k>>2) is
// stored at offset ((q&3)<<3) + ((q>>2)<<2). A lane's 8 frag elements
// {4g..4g+3, 16+4g..19+4g} land contiguously at [8g..8g+7] -> one 16B load.
static __device__ __forceinline__ bf16x8 ldfrag128(const ushort* p) {
  union { bf16x8 v; uint4 u; } r;
  r.u = *(const uint4*)p;
  return r.v;
}
// async global->LDS, 16B per lane; lds dest = base + lane*16 (wave-uniform base)
static __device__ __forceinline__ void gll16(const ushort* g, ushort* l) {
  __builtin_amdgcn_global_load_lds(
      (const __attribute__((address_space(1))) uint32_t*)g,
      (__attribute__((address_space(3))) uint32_t*)l, 16, 0, 0);
}

// ---------------- fused fp32->bf16 conversion, frag-interleaved output -------------
__global__ void cvt_all(const float* __restrict__ x,  const float* __restrict__ wq,
                        const float* __restrict__ wk, const float* __restrict__ wv,
                        const float* __restrict__ wo,
                        ushort* __restrict__ xb, ushort* __restrict__ Wb,
                        ushort* __restrict__ Wob) {
  int g = (blockIdx.x * 256 + threadIdx.x) * 4;   // < 6815744, 4-aligned
  float4 v; ushort* dst; int j;
  if (g < 2097152) {
    v = *(const float4*)(x + g); dst = xb; j = g;
  } else if (g < 5767168) {
    j = g - 2097152;
    const float* src = (j < 2097152) ? (wq + j)
                     : (j < 3145728) ? (wk + (j - 2097152))
                                     : (wv + (j - 3145728));
    v = *(const float4*)src; dst = Wb;
  } else {
    j = g - 5767168;
    v = *(const float4*)(wo + j); dst = Wob;
  }
  int q = (j & 31) >> 2;                         // quad within 32-block
  int jp = (j & ~31) + ((q & 3) << 3) + ((q >> 2) << 2);
  ushort4 o4;
  o4.x = f2bf(v.x); o4.y = f2bf(v.y); o4.z = f2bf(v.z); o4.w = f2bf(v.w);
  *(ushort4*)(dst + jp) = o4;
}

__global__ void lam_kernel(const float* __restrict__ lq1, const float* __restrict__ lk1,
                           const float* __restrict__ lq2, const float* __restrict__ lk2,
                           float* __restrict__ lam) {
  int lane = threadIdx.x;  // 64 threads
  float p1 = lq1[lane] * lk1[lane];
  float p2 = lq2[lane] * lk2[lane];
  #pragma unroll
  for (int off = 32; off >= 1; off >>= 1) {
    p1 += __shfl_down(p1, off);
    p2 += __shfl_down(p2, off);
  }
  if (lane == 0) *lam = expf(p1) - expf(p2) + LAMBDA_INIT_F;
}

// ---------------- GEMM (m97 + T1 swizzle), frag-interleaved inputs, b128 reads -----
template<int BF16OUT>
__global__ __launch_bounds__(256) void gemm_bt(const ushort* __restrict__ A,
                                               const ushort* __restrict__ W,
                                               void* __restrict__ Cout,
                                               int M, int N, int K) {
  __shared__ __align__(16) ushort As[128 * 32];
  __shared__ __align__(16) ushort Ws[128 * 32];
  const int tid  = threadIdx.x;
  const int lane = tid & 63;
  const int w    = tid >> 6;
  const int wr   = w >> 1, wc = w & 1;
  const int nwg = gridDim.x * gridDim.y;
  int id  = blockIdx.x * gridDim.y + blockIdx.y;
  int sw  = (id & 7) * (nwg >> 3) + (id >> 3);
  const int bm = (sw % gridDim.y) * 128;
  const int bn = (sw / gridDim.y) * 128;
  const int fr = lane & 15;
  const int fg = (lane >> 4) * 4;
  const int g8 = (lane >> 4) * 8;

  f32x4 acc[4][4];
  #pragma unroll
  for (int m = 0; m < 4; ++m)
    #pragma unroll
    for (int n = 0; n < 4; ++n) acc[m][n] = zero4();

  const int col  = (lane & 3) * 8;
  const int row0 = w * 16 + (lane >> 2);
  const int row1 = row0 + 64;
  const ushort* ga0 = A + (size_t)(bm + row0) * K + col;
  const ushort* ga1 = A + (size_t)(bm + row1) * K + col;
  const ushort* gw0 = W + (size_t)(bn + row0) * K + col;
  const ushort* gw1 = W + (size_t)(bn + row1) * K + col;
  ushort* la0 = As + (w * 512);
  ushort* la1 = As + (w * 512) + 2048;
  ushort* lw0 = Ws + (w * 512);
  ushort* lw1 = Ws + (w * 512) + 2048;

  for (int k0 = 0; k0 < K; k0 += 32) {
    gll16(ga0 + k0, la0);
    gll16(ga1 + k0, la1);
    gll16(gw0 + k0, lw0);
    gll16(gw1 + k0, lw1);
    __syncthreads();
    bf16x8 af[4], bfr[4];
    #pragma unroll
    for (int m = 0; m < 4; ++m) af[m]  = ldfrag128(&As[(wr*64 + m*16 + fr) * 32 + g8]);
    #pragma unroll
    for (int n = 0; n < 4; ++n) bfr[n] = ldfrag128(&Ws[(wc*64 + n*16 + fr) * 32 + g8]);
    #pragma unroll
    for (int m = 0; m < 4; ++m)
      #pragma unroll
      for (int n = 0; n < 4; ++n)
        acc[m][n] = __builtin_amdgcn_mfma_f32_16x16x32_bf16(af[m], bfr[n], acc[m][n], 0, 0, 0);
    __syncthreads();
  }

  #pragma unroll
  for (int m = 0; m < 4; ++m)
    #pragma unroll
    for (int n = 0; n < 4; ++n)
      #pragma unroll
      for (int i = 0; i < 4; ++i) {
        int row = bm + wr*64 + m*16 + fg + i;
        int colg = bn + wc*64 + n*16 + fr;
        float v = acc[m][n][i];
        if (BF16OUT) ((ushort*)Cout)[(size_t)row * N + colg] = f2bf(v);
        else         ((float*)Cout)[(size_t)row * N + colg]  = v;
      }
}

// ---------------- fused RoPE Q, RoPE K, pack V -> frag-interleaved layouts ---------
// Q scaled by 0.125*log2(e). Qr/Kr: d-dim permuted per 32-block; Vt: t-dim permuted.
__global__ void reorg(const ushort* __restrict__ QKV, ushort* __restrict__ Qr,
                      ushort* __restrict__ Kr, ushort* __restrict__ Vt,
                      const float* __restrict__ fc, const float* __restrict__ fs) {
  int idx = blockIdx.x * 256 + threadIdx.x;   // < 917504
  if (idx < 786432) {
    // RoPE, 4 interleaved pairs = 8 consecutive logical d per thread
    int nheads, col_off; ushort* dst; float scale; int id;
    if (idx < 524288) { id = idx * 4; nheads = NHEAD; col_off = 0; dst = Qr; scale = QSCALE_EXP2; }
    else { id = (idx - 524288) * 4; nheads = NKVH; col_off = 2048; dst = Kr; scale = 1.0f; }
    int per_t = nheads * 64;
    int t  = id / per_t;
    int r  = id - t * per_t;
    int hh = r >> 6;
    int c2 = (r >> 5) & 1;
    int j  = r & 31;                      // multiple of 4; logical d0 = 2j
    int cl = col_off + hh * 128 + c2 * 64 + 2 * j;
    uint4 raw = *(const uint4*)(QKV + (size_t)t * QKVN + cl);
    const ushort* rp = (const ushort*)&raw;
    float c4[4], s4[4];
    *(float4*)c4 = *(const float4*)(fc + t * 32 + j);
    *(float4*)s4 = *(const float4*)(fs + t * 32 + j);
    ushort outv[8];
    #pragma unroll
    for (int p = 0; p < 4; ++p) {
      float rv = bf2f(rp[2*p]), iv = bf2f(rp[2*p + 1]);
      outv[2*p]     = f2bf((rv * c4[p] - iv * s4[p]) * scale);
      outv[2*p + 1] = f2bf((rv * s4[p] + iv * c4[p]) * scale);
    }
    int d0 = 2 * j;
    int o  = d0 & 31;                     // 0,8,16,24
    int q0 = o >> 2;                      // 0,2,4,6
    int s0 = ((q0 & 3) << 3) + ((q0 >> 2) << 2);
    int s1 = (((q0+1) & 3) << 3) + (((q0+1) >> 2) << 2);
    size_t ob = ((size_t)(c2 * nheads + hh) * T_SEQ + t) * HDIM + (d0 & ~31);
    *(uint2*)(dst + ob + s0) = *(const uint2*)(outv);
    *(uint2*)(dst + ob + s1) = *(const uint2*)(outv + 4);
  } else {
    // V transpose: 8 t-consecutive elems, t-permuted within 32-blocks
    int id = (idx - 786432) * 8;           // < 1048576
    int t = id & (T_SEQ - 1);              // multiple of 8
    int rest = id >> 11;                   // kh*64 + d
    ushort outv[8];
    #pragma unroll
    for (int p = 0; p < 8; ++p) outv[p] = QKV[(size_t)(t + p) * QKVN + 3072 + rest];
    int o  = t & 31;
    int q0 = o >> 2;
    int s0 = ((q0 & 3) << 3) + ((q0 >> 2) << 2);
    int s1 = (((q0+1) & 3) << 3) + (((q0+1) >> 2) << 2);
    size_t ob = (size_t)rest * T_SEQ + (t & ~31);
    *(uint2*)(Vt + ob + s0) = *(const uint2*)(outv);
    *(uint2*)(Vt + ob + s1) = *(const uint2*)(outv + 4);
  }
}

// ---------------- flash attention: two KV tiles per iteration, joint softmax -------
// 512 blocks = (head, qb). Wave w: stream st = w>>1, q-half qh = w&1 (two 16-row
// chunks qs). Main loop processes KV tiles in PAIRS: both QK^T blocks issue
// back-to-back (2x ILP), ONE joint online-softmax covers 128 keys (one max chain,
// one rescale), then both PVs. Diagonal + odd leftover use a single-tile path.
// K/V fragments direct from L2 (frag-interleaved global). No in-loop LDS/barriers.
__global__ __launch_bounds__(256, 2) void attn_kernel(const ushort* __restrict__ Qr,
                                                      const ushort* __restrict__ Kr,
                                                      const ushort* __restrict__ Vt,
                                                      const float* __restrict__ lamp,
                                                      float* __restrict__ Yf,
                                                      float* __restrict__ part) {
  const int bx = blockIdx.x;          // 0..511
  const int h  = bx & 15;
  const int jb = bx >> 4;             // pair (jb, jb+16) sums to 32 tiles
  const int qb = (jb < 16) ? (31 - jb) : (jb - 16);
  const int kh = h >> 1;
  const int tid = threadIdx.x;
  const int lane = tid & 63;
  const int w   = tid >> 6;
  const int st  = w >> 1;             // stream 0/1
  const int qh  = w & 1;              // q-half 0/1
  const int fr  = lane & 15;
  const int fg  = (lane >> 4) * 4;
  const int g8  = (lane >> 4) * 8;

  __shared__ float ob[64 * 64];       // epilogue O2 exchange (16 KB)
  __shared__ float sb[8];

  // Q fragments for this wave's stream, two 16-q chunks (frag-interleaved global)
  bf16x8 qf[2][2];                     // [qs][ks]
  #pragma unroll
  for (int qs = 0; qs < 2; ++qs) {
    const int row = qb * 64 + qh * 32 + qs * 16 + fr;
    const ushort* qp = Qr + ((size_t)(st * NHEAD + h) * T_SEQ + row) * HDIM;
    qf[qs][0] = ldfrag128(qp + g8);
    qf[qs][1] = ldfrag128(qp + 32 + g8);
  }

  float m_[2] = {-__builtin_inff(), -__builtin_inff()};
  float l_[2] = {0.f, 0.f};
  f32x4 o_[2][4];
  #pragma unroll
  for (int qs = 0; qs < 2; ++qs)
    #pragma unroll
    for (int dn = 0; dn < 4; ++dn) o_[qs][dn] = zero4();

  // per-lane fragment base pointers (row picked by fr, 16B chunk by g8)
  const ushort* Kbase = Kr + ((size_t)(st * NKVH + kh) * T_SEQ + fr) * HDIM + g8;
  const ushort* Vbase = Vt + ((size_t)(kh * 64 + fr) * T_SEQ) + g8;

// single-tile body (R12-proven), mask optional
#define SINGLE_TILE(KT, DOMASK) do {                                          \
    const int kvb_ = (KT) * 64;                                               \
    bf16x8 kf_[4][2], vf_[4][2];                                              \
    _Pragma("unroll")                                                         \
    for (int n_ = 0; n_ < 4; ++n_) {                                          \
      const ushort* kp_ = Kbase + (size_t)(kvb_ + n_ * 16) * HDIM;            \
      kf_[n_][0] = ldfrag128(kp_);                                            \
      kf_[n_][1] = ldfrag128(kp_ + 32);                                       \
      const ushort* vp_ = Vbase + (size_t)(n_ * 16) * T_SEQ + kvb_;           \
      vf_[n_][0] = ldfrag128(vp_);                                            \
      vf_[n_][1] = ldfrag128(vp_ + 32);                                       \
    }                                                                         \
    float sv_[2][4][4];                                                       \
    __builtin_amdgcn_s_setprio(1);                                            \
    _Pragma("unroll")                                                         \
    for (int n_ = 0; n_ < 4; ++n_) {                                          \
      f32x4 a0_ = zero4(), a1_ = zero4();                                     \
      _Pragma("unroll")                                                       \
      for (int ks_ = 0; ks_ < 2; ++ks_) {                                     \
        a0_ = __builtin_amdgcn_mfma_f32_16x16x32_bf16(kf_[n_][ks_], qf[0][ks_], a0_, 0, 0, 0); \
        a1_ = __builtin_amdgcn_mfma_f32_16x16x32_bf16(kf_[n_][ks_], qf[1][ks_], a1_, 0, 0, 0); \
      }                                                                       \
      _Pragma("unroll")                                                       \
      for (int i_ = 0; i_ < 4; ++i_) { sv_[0][n_][i_] = a0_[i_]; sv_[1][n_][i_] = a1_[i_]; } \
    }                                                                         \
    __builtin_amdgcn_s_setprio(0);                                            \
    if (DOMASK) {                                                             \
      _Pragma("unroll")                                                       \
      for (int qs_ = 0; qs_ < 2; ++qs_) {                                     \
        const int qloc_ = qh*32 + qs_*16 + fr;                                \
        _Pragma("unroll")                                                     \
        for (int n_ = 0; n_ < 4; ++n_)                                        \
          _Pragma("unroll")                                                   \
          for (int i_ = 0; i_ < 4; ++i_)                                      \
            if (n_*16 + fg + i_ > qloc_) sv_[qs_][n_][i_] = -__builtin_inff();\
      }                                                                       \
    }                                                                         \
    bf16x8 pa_[2][2];                                                         \
    _Pragma("unroll")                                                         \
    for (int qs_ = 0; qs_ < 2; ++qs_) {                                       \
      float rm_ = -__builtin_inff();                                          \
      _Pragma("unroll")                                                       \
      for (int n_ = 0; n_ < 4; ++n_)                                          \
        _Pragma("unroll")                                                     \
        for (int i_ = 0; i_ < 4; ++i_) rm_ = fmaxf(rm_, sv_[qs_][n_][i_]);    \
      rm_ = fmaxf(rm_, __shfl_xor(rm_, 16));                                  \
      rm_ = fmaxf(rm_, __shfl_xor(rm_, 32));                                  \
      if (!__all(rm_ <= m_[qs_] + 8.f)) {                                     \
        float mnew_ = fmaxf(m_[qs_], rm_);                                    \
        float sc_ = __builtin_amdgcn_exp2f(m_[qs_] - mnew_);                  \
        m_[qs_] = mnew_;                                                      \
        l_[qs_] *= sc_;                                                       \
        float scs_[4];                                                        \
        _Pragma("unroll")                                                     \
        for (int i_ = 0; i_ < 4; ++i_) scs_[i_] = __shfl(sc_, fg + i_);       \
        _Pragma("unroll")                                                     \
        for (int dn_ = 0; dn_ < 4; ++dn_)                                     \
          _Pragma("unroll")                                                   \
          for (int i_ = 0; i_ < 4; ++i_) o_[qs_][dn_][i_] *= scs_[i_];        \
      }                                                                       \
      float rs_ = 0.f;                                                        \
      _Pragma("unroll")                                                       \
      for (int n_ = 0; n_ < 4; ++n_)                                          \
        _Pragma("unroll")                                                     \
        for (int i_ = 0; i_ < 4; ++i_) {                                      \
          float p_ = __builtin_amdgcn_exp2f(sv_[qs_][n_][i_] - m_[qs_]);      \
          sv_[qs_][n_][i_] = p_; rs_ += p_;                                   \
        }                                                                     \
      rs_ += __shfl_xor(rs_, 16);                                             \
      rs_ += __shfl_xor(rs_, 32);                                             \
      l_[qs_] += rs_;                                                         \
      _Pragma("unroll")                                                       \
      for (int ks_ = 0; ks_ < 2; ++ks_)                                       \
        _Pragma("unroll")                                                     \
        for (int n2_ = 0; n2_ < 2; ++n2_)                                     \
          _Pragma("unroll")                                                   \
          for (int i_ = 0; i_ < 4; ++i_)                                      \
            pa_[qs_][ks_][n2_*4 + i_] = (__bf16)sv_[qs_][2*ks_ + n2_][i_];    \
    }                                                                         \
    __builtin_amdgcn_s_setprio(1);                                            \
    _Pragma("unroll")                                                         \
    for (int ks_ = 0; ks_ < 2; ++ks_)                                         \
      _Pragma("unroll")                                                       \
      for (int dn_ = 0; dn_ < 4; ++dn_) {                                     \
        o_[0][dn_] = __builtin_amdgcn_mfma_f32_16x16x32_bf16(pa_[0][ks_], vf_[dn_][ks_], o_[0][dn_], 0, 0, 0); \
        o_[1][dn_] = __builtin_amdgcn_mfma_f32_16x16x32_bf16(pa_[1][ks_], vf_[dn_][ks_], o_[1][dn_], 0, 0, 0); \
      }                                                                       \
    __builtin_amdgcn_s_setprio(0);                                            \
  } while (0)

  const int nnd = qb;                 // non-diagonal tiles: kt in [0, qb)
  int kt = 0;
  for (; kt + 1 < nnd; kt += 2) {
    const int ka = kt * 64, kb = ka + 64;
    // issue ALL loads for both tiles up front
    bf16x8 kfA[4][2], vfA[4][2], kfB[4][2], vfB[4][2];
    #pragma unroll
    for (int n = 0; n < 4; ++n) {
      const ushort* kpA = Kbase + (size_t)(ka + n * 16) * HDIM;
      const ushort* kpB = Kbase + (size_t)(kb + n * 16) * HDIM;
      kfA[n][0] = ldfrag128(kpA);  kfA[n][1] = ldfrag128(kpA + 32);
      kfB[n][0] = ldfrag128(kpB);  kfB[n][1] = ldfrag128(kpB + 32);
      const ushort* vpA = Vbase + (size_t)(n * 16) * T_SEQ + ka;
      vfA[n][0] = ldfrag128(vpA);  vfA[n][1] = ldfrag128(vpA + 32);
      const ushort* vpB = vpA + 64;
      vfB[n][0] = ldfrag128(vpB);  vfB[n][1] = ldfrag128(vpB + 32);
    }
    // both QK^T blocks (independent)
    float svA[2][4][4], svB[2][4][4];
    __builtin_amdgcn_s_setprio(1);
    #pragma unroll
    for (int n = 0; n < 4; ++n) {
      f32x4 a0 = zero4(), a1 = zero4(), b0 = zero4(), b1 = zero4();
      #pragma unroll
      for (int ks = 0; ks < 2; ++ks) {
        a0 = __builtin_amdgcn_mfma_f32_16x16x32_bf16(kfA[n][ks], qf[0][ks], a0, 0, 0, 0);
        a1 = __builtin_amdgcn_mfma_f32_16x16x32_bf16(kfA[n][ks], qf[1][ks], a1, 0, 0, 0);
        b0 = __builtin_amdgcn_mfma_f32_16x16x32_bf16(kfB[n][ks], qf[0][ks], b0, 0, 0, 0);
        b1 = __builtin_amdgcn_mfma_f32_16x16x32_bf16(kfB[n][ks], qf[1][ks], b1, 0, 0, 0);
      }
      #pragma unroll
      for (int i = 0; i < 4; ++i) {
        svA[0][n][i] = a0[i]; svA[1][n][i] = a1[i];
        svB[0][n][i] = b0[i]; svB[1][n][i] = b1[i];
      }
    }
    __builtin_amdgcn_s_setprio(0);

    // joint online-softmax over both tiles (one max/rescale per chunk)
    bf16x8 paA[2][2], paB[2][2];
    #pragma unroll
    for (int qs = 0; qs < 2; ++qs) {
      float rm = -__builtin_inff();
      #pragma unroll
      for (int n = 0; n < 4; ++n)
        #pragma unroll
        for (int i = 0; i < 4; ++i) {
          rm = fmaxf(rm, svA[qs][n][i]);
          rm = fmaxf(rm, svB[qs][n][i]);
        }
      rm = fmaxf(rm, __shfl_xor(rm, 16));
      rm = fmaxf(rm, __shfl_xor(rm, 32));
      if (!__all(rm <= m_[qs] + 8.f)) {   // defer-max (exp2 domain, THR=8)
        float mnew = fmaxf(m_[qs], rm);
        float sc = __builtin_amdgcn_exp2f(m_[qs] - mnew);
        m_[qs] = mnew;
        l_[qs] *= sc;
        float scs[4];
        #pragma unroll
        for (int i = 0; i < 4; ++i) scs[i] = __shfl(sc, fg + i);
        #pragma unroll
        for (int dn = 0; dn < 4; ++dn)
          #pragma unroll
          for (int i = 0; i < 4; ++i) o_[qs][dn][i] *= scs[i];
      }
      float rs = 0.f;
      #pragma unroll
      for (int n = 0; n < 4; ++n)
        #pragma unroll
        for (int i = 0; i < 4; ++i) {
          float pA = __builtin_amdgcn_exp2f(svA[qs][n][i] - m_[qs]);
          float pB = __builtin_amdgcn_exp2f(svB[qs][n][i] - m_[qs]);
          svA[qs][n][i] = pA; svB[qs][n][i] = pB;
          rs += pA + pB;
        }
      rs += __shfl_xor(rs, 16);
      rs += __shfl_xor(rs, 32);
      l_[qs] += rs;
      #pragma unroll
      for (int ks = 0; ks < 2; ++ks)
        #pragma unroll
        for (int n2 = 0; n2 < 2; ++n2)
          #pragma unroll
          for (int i = 0; i < 4; ++i) {
            paA[qs][ks][n2*4 + i] = (__bf16)svA[qs][2*ks + n2][i];
            paB[qs][ks][n2*4 + i] = (__bf16)svB[qs][2*ks + n2][i];
          }
    }

    // both PVs
    __builtin_amdgcn_s_setprio(1);
    #pragma unroll
    for (int ks = 0; ks < 2; ++ks)
      #pragma unroll
      for (int dn = 0; dn < 4; ++dn) {
        o_[0][dn] = __builtin_amdgcn_mfma_f32_16x16x32_bf16(paA[0][ks], vfA[dn][ks], o_[0][dn], 0, 0, 0);
        o_[1][dn] = __builtin_amdgcn_mfma_f32_16x16x32_bf16(paA[1][ks], vfA[dn][ks], o_[1][dn], 0, 0, 0);
      }
    #pragma unroll
    for (int ks = 0; ks < 2; ++ks)
      #pragma unroll
      for (int dn = 0; dn < 4; ++dn) {
        o_[0][dn] = __builtin_amdgcn_mfma_f32_16x16x32_bf16(paB[0][ks], vfB[dn][ks], o_[0][dn], 0, 0, 0);
        o_[1][dn] = __builtin_amdgcn_mfma_f32_16x16x32_bf16(paB[1][ks], vfB[dn][ks], o_[1][dn], 0, 0, 0);
      }
    __builtin_amdgcn_s_setprio(0);
  }
  if (kt < nnd) { SINGLE_TILE(kt, 0); ++kt; }
  SINGLE_TILE(qb, 1);                 // diagonal tile (masked)
#undef SINGLE_TILE

  // epilogue: normalize; exchange stream-1 O via LDS; combine + Yf + LN partials
  float iq[2][4];
  #pragma unroll
  for (int qs = 0; qs < 2; ++qs) {
    float inv = __builtin_amdgcn_rcpf(l_[qs]);
    #pragma unroll
    for (int i = 0; i < 4; ++i) iq[qs][i] = __shfl(inv, fg + i);
  }
  __syncthreads();
  if (st == 1) {
    #pragma unroll
    for (int qs = 0; qs < 2; ++qs)
      #pragma unroll
      for (int dn = 0; dn < 4; ++dn)
        #pragma unroll
        for (int i = 0; i < 4; ++i)
          ob[(qh*32 + qs*16 + fg + i)*64 + dn*16 + fr] = o_[qs][dn][i] * iq[qs][i];
  }
  __syncthreads();
  if (st == 0) {
    const float lam = *lamp;
    float s = 0.f, s2 = 0.f;
    #pragma unroll
    for (int qs = 0; qs < 2; ++qs)
      #pragma unroll
      for (int dn = 0; dn < 4; ++dn)
        #pragma unroll
        for (int i = 0; i < 4; ++i) {
          int r64 = qh*32 + qs*16 + fg + i;
          int d   = dn*16 + fr;
          float v = o_[qs][dn][i] * iq[qs][i] - lam * ob[r64*64 + d];
          Yf[(size_t)(qb*64 + r64) * DIM + h*64 + d] = v;
          s += v; s2 += v * v;
        }
    #pragma unroll
    for (int off = 1; off <= 32; off <<= 1) {
      s  += __shfl_xor(s, off);
      s2 += __shfl_xor(s2, off);
    }
    if (lane == 0) { sb[w] = s; sb[4 + w] = s2; }   // w in {0,1}
  }
  __syncthreads();
  if (tid == 0) {
    part[bx]       = sb[0] + sb[1];
    part[512 + bx] = sb[4] + sb[5];
  }
}

// ---------------- finalize per-head stats ----------------
__global__ void stats_final(const float* __restrict__ part, float* __restrict__ stat) {
  int hh = threadIdx.x;
  if (hh < 16) {
    float S = 0.f, S2 = 0.f;
    #pragma unroll
    for (int j = 0; j < 32; ++j) { S += part[j*16 + hh]; S2 += part[512 + j*16 + hh]; }
    const float N = (float)(T_SEQ * HDIM);
    float mean = S / N;
    float var  = S2 / N - mean * mean;
    stat[hh]      = mean;
    stat[16 + hh] = rsqrtf(var + 1e-5f);
  }
}

// Yb written frag-interleaved (gemm2 expects it)
__global__ void norm_cvt(const float* __restrict__ Y, const float* __restrict__ stats,
                         ushort* __restrict__ Yb) {
  int idx = (blockIdx.x * 256 + threadIdx.x) * 4;   // < T*DIM, 4-aligned
  int col = idx & (DIM - 1);
  int h = col >> 6;
  float mean = stats[h], isd = stats[16 + h] * ONE_MINUS_LI;
  float4 v = *(const float4*)(Y + idx);
  ushort4 o4;
  o4.x = f2bf((v.x - mean) * isd);
  o4.y = f2bf((v.y - mean) * isd);
  o4.z = f2bf((v.z - mean) * isd);
  o4.w = f2bf((v.w - mean) * isd);
  int q = (col & 31) >> 2;
  int idxp = (idx & ~31) + ((q & 3) << 3) + ((q >> 2) << 2);
  *(ushort4*)(Yb + idxp) = o4;
}

// ---------------- launch ----------------
extern "C" void kernel_launch(void* const* d_in, const int* in_sizes, int n_in,
                              void* d_out, int out_size, void* d_ws, size_t ws_size,
                              hipStream_t stream) {
  const float* x   = (const float*)d_in[0];
  const float* fc  = (const float*)d_in[1];
  const float* fs  = (const float*)d_in[2];
  const float* wq  = (const float*)d_in[3];
  const float* wk  = (const float*)d_in[4];
  const float* wv  = (const float*)d_in[5];
  const float* wo  = (const float*)d_in[6];
  const float* lq1 = (const float*)d_in[7];
  const float* lk1 = (const float*)d_in[8];
  const float* lq2 = (const float*)d_in[9];
  const float* lk2 = (const float*)d_in[10];
  float* out = (float*)d_out;

  char* ws = (char*)d_ws;
  const size_t OFF_WOB  = 0;                 // 2 MB, live till end
  const size_t OFF_XB   = 2097152;           // 4 MB, dead after gemm1
  const size_t OFF_WB   = 6291456;           // 7 MB, dead after gemm1
  const size_t OFF_QKV  = 13631488;          // 14.68 MB, dead after reorg
  const size_t OFF_QR   = 28311552;          // 8 MB
  const size_t OFF_KR   = 36700160;          // 4 MB
  const size_t OFF_VT   = 40894464;          // 2 MB
  const size_t OFF_Y    = 18874368;          // 8 MB over dead QKV tail
  const size_t OFF_YB   = 42991616;          // 4 MB
  const size_t OFF_ST   = 47185920;          // stats + lam + partials

  ushort* xb   = (ushort*)(ws + OFF_XB);
  ushort* Wb   = (ushort*)(ws + OFF_WB);
  ushort* Wob  = (ushort*)(ws + OFF_WOB);
  ushort* QKVb = (ushort*)(ws + OFF_QKV);
  ushort* Qr   = (ushort*)(ws + OFF_QR);
  ushort* Kr   = (ushort*)(ws + OFF_KR);
  ushort* Vt   = (ushort*)(ws + OFF_VT);
  float*  Yf   = (float*)(ws + OFF_Y);
  ushort* Yb   = (ushort*)(ws + OFF_YB);
  float*  stat = (float*)(ws + OFF_ST);
  float*  lamp = stat + 32;
  float*  part = stat + 64;                  // 1024 floats

  cvt_all<<<6656, 256, 0, stream>>>(x, wq, wk, wv, wo, xb, Wb, Wob);
  lam_kernel<<<1, 64, 0, stream>>>(lq1, lk1, lq2, lk2, lamp);

  gemm_bt<1><<<dim3(QKVN/128, T_SEQ/128), 256, 0, stream>>>(xb, Wb, QKVb, T_SEQ, QKVN, DIM);

  reorg<<<3584, 256, 0, stream>>>(QKVb, Qr, Kr, Vt, fc, fs);

  attn_kernel<<<512, 256, 0, stream>>>(Qr, Kr, Vt, lamp, Yf, part);

  stats_final<<<1, 64, 0, stream>>>(part, stat);
  norm_cvt<<<2048, 256, 0, stream>>>(Yf, stat, Yb);

  gemm_bt<0><<<dim3(DIM/128, T_SEQ/128), 256, 0, stream>>>(Yb, Wob, out, T_SEQ, DIM, DIM);
}

// Round 19
// 141.239 us; speedup vs baseline: 1.3036x; 1.0476x over previous
//
#include <hip/hip_runtime.h>
#include <hip/hip_bf16.h>
#include <cstdint>

#define T_SEQ 2048
#define DIM   1024
#define NHEAD 16
#define NKVH  8
#define HDIM  64
#define QKVN  3584   // 2048 (q) + 1024 (k) + 512 (v)

static constexpr float LAMBDA_INIT_F = 0.3555090675909693f;
static constexpr float ONE_MINUS_LI  = 0.6444909324090307f;
static constexpr float QSCALE_EXP2   = 0.1803368801111144f;  // 0.125 * log2(e)

typedef __bf16 bf16x8 __attribute__((ext_vector_type(8)));
typedef float  f32x4  __attribute__((ext_vector_type(4)));

static __device__ __forceinline__ ushort f2bf(float f) {
  union { float f; uint32_t u; } x; x.f = f;
  uint32_t u = x.u;
  uint32_t r = (u + 0x7fffu + ((u >> 16) & 1u)) >> 16;
  return (ushort)r;
}
static __device__ __forceinline__ float bf2f(ushort u) {
  union { uint32_t u; float f; } x; x.u = ((uint32_t)u) << 16; return x.f;
}
static __device__ __forceinline__ f32x4 zero4() {
  f32x4 z = {0.f, 0.f, 0.f, 0.f}; return z;
}
// Fragment-interleaved layout: within each 32-element k-block, quad q (=k>>2) is
// stored at offset ((q&3)<<3) + ((q>>2)<<2). A lane's 8 frag elements
// {4g..4g+3, 16+4g..19+4g} land contiguously at [8g..8g+7] -> one 16B load.
static __device__ __forceinline__ bf16x8 ldfrag128(const ushort* p) {
  union { bf16x8 v; uint4 u; } r;
  r.u = *(const uint4*)p;
  return r.v;
}
// async global->LDS, 16B per lane; lds dest = base + lane*16 (wave-uniform base)
static __device__ __forceinline__ void gll16(const ushort* g, ushort* l) {
  __builtin_amdgcn_global_load_lds(
      (const __attribute__((address_space(1))) uint32_t*)g,
      (__attribute__((address_space(3))) uint32_t*)l, 16, 0, 0);
}

// ---------------- fused fp32->bf16 conversion, frag-interleaved output -------------
__global__ void cvt_all(const float* __restrict__ x,  const float* __restrict__ wq,
                        const float* __restrict__ wk, const float* __restrict__ wv,
                        const float* __restrict__ wo,
                        ushort* __restrict__ xb, ushort* __restrict__ Wb,
                        ushort* __restrict__ Wob) {
  int g = (blockIdx.x * 256 + threadIdx.x) * 4;   // < 6815744, 4-aligned
  float4 v; ushort* dst; int j;
  if (g < 2097152) {
    v = *(const float4*)(x + g); dst = xb; j = g;
  } else if (g < 5767168) {
    j = g - 2097152;
    const float* src = (j < 2097152) ? (wq + j)
                     : (j < 3145728) ? (wk + (j - 2097152))
                                     : (wv + (j - 3145728));
    v = *(const float4*)src; dst = Wb;
  } else {
    j = g - 5767168;
    v = *(const float4*)(wo + j); dst = Wob;
  }
  int q = (j & 31) >> 2;                         // quad within 32-block
  int jp = (j & ~31) + ((q & 3) << 3) + ((q >> 2) << 2);
  ushort4 o4;
  o4.x = f2bf(v.x); o4.y = f2bf(v.y); o4.z = f2bf(v.z); o4.w = f2bf(v.w);
  *(ushort4*)(dst + jp) = o4;
}

__global__ void lam_kernel(const float* __restrict__ lq1, const float* __restrict__ lk1,
                           const float* __restrict__ lq2, const float* __restrict__ lk2,
                           float* __restrict__ lam) {
  int lane = threadIdx.x;  // 64 threads
  float p1 = lq1[lane] * lk1[lane];
  float p2 = lq2[lane] * lk2[lane];
  #pragma unroll
  for (int off = 32; off >= 1; off >>= 1) {
    p1 += __shfl_down(p1, off);
    p2 += __shfl_down(p2, off);
  }
  if (lane == 0) *lam = expf(p1) - expf(p2) + LAMBDA_INIT_F;
}

// ---------------- GEMM (m97 + T1 swizzle), BK=64: two K-panels per barrier pair ----
// LDS = [kk][128][32] per matrix (two sequential 8KB panels) so the proven
// conflict-free frag reads and linear gll16 destinations are preserved; barriers
// per MFMA halve vs BK=32.
template<int BF16OUT>
__global__ __launch_bounds__(256) void gemm_bt(const ushort* __restrict__ A,
                                               const ushort* __restrict__ W,
                                               void* __restrict__ Cout,
                                               int M, int N, int K) {
  __shared__ __align__(16) ushort As[2 * 128 * 32];
  __shared__ __align__(16) ushort Ws[2 * 128 * 32];
  const int tid  = threadIdx.x;
  const int lane = tid & 63;
  const int w    = tid >> 6;
  const int wr   = w >> 1, wc = w & 1;
  const int nwg = gridDim.x * gridDim.y;
  int id  = blockIdx.x * gridDim.y + blockIdx.y;
  int sw  = (id & 7) * (nwg >> 3) + (id >> 3);
  const int bm = (sw % gridDim.y) * 128;
  const int bn = (sw / gridDim.y) * 128;
  const int fr = lane & 15;
  const int fg = (lane >> 4) * 4;
  const int g8 = (lane >> 4) * 8;

  f32x4 acc[4][4];
  #pragma unroll
  for (int m = 0; m < 4; ++m)
    #pragma unroll
    for (int n = 0; n < 4; ++n) acc[m][n] = zero4();

  const int col  = (lane & 3) * 8;
  const int row0 = w * 16 + (lane >> 2);
  const int row1 = row0 + 64;
  const ushort* ga0 = A + (size_t)(bm + row0) * K + col;
  const ushort* ga1 = A + (size_t)(bm + row1) * K + col;
  const ushort* gw0 = W + (size_t)(bn + row0) * K + col;
  const ushort* gw1 = W + (size_t)(bn + row1) * K + col;
  ushort* la0 = As + (w * 512);
  ushort* la1 = As + (w * 512) + 2048;
  ushort* la2 = As + 4096 + (w * 512);
  ushort* la3 = As + 4096 + (w * 512) + 2048;
  ushort* lw0 = Ws + (w * 512);
  ushort* lw1 = Ws + (w * 512) + 2048;
  ushort* lw2 = Ws + 4096 + (w * 512);
  ushort* lw3 = Ws + 4096 + (w * 512) + 2048;

  for (int k0 = 0; k0 < K; k0 += 64) {
    gll16(ga0 + k0,      la0);
    gll16(ga1 + k0,      la1);
    gll16(ga0 + k0 + 32, la2);
    gll16(ga1 + k0 + 32, la3);
    gll16(gw0 + k0,      lw0);
    gll16(gw1 + k0,      lw1);
    gll16(gw0 + k0 + 32, lw2);
    gll16(gw1 + k0 + 32, lw3);
    __syncthreads();
    #pragma unroll
    for (int kk = 0; kk < 2; ++kk) {
      bf16x8 af[4], bfr[4];
      #pragma unroll
      for (int m = 0; m < 4; ++m)
        af[m]  = ldfrag128(&As[kk*4096 + (wr*64 + m*16 + fr) * 32 + g8]);
      #pragma unroll
      for (int n = 0; n < 4; ++n)
        bfr[n] = ldfrag128(&Ws[kk*4096 + (wc*64 + n*16 + fr) * 32 + g8]);
      #pragma unroll
      for (int m = 0; m < 4; ++m)
        #pragma unroll
        for (int n = 0; n < 4; ++n)
          acc[m][n] = __builtin_amdgcn_mfma_f32_16x16x32_bf16(af[m], bfr[n], acc[m][n], 0, 0, 0);
    }
    __syncthreads();
  }

  #pragma unroll
  for (int m = 0; m < 4; ++m)
    #pragma unroll
    for (int n = 0; n < 4; ++n)
      #pragma unroll
      for (int i = 0; i < 4; ++i) {
        int row = bm + wr*64 + m*16 + fg + i;
        int colg = bn + wc*64 + n*16 + fr;
        float v = acc[m][n][i];
        if (BF16OUT) ((ushort*)Cout)[(size_t)row * N + colg] = f2bf(v);
        else         ((float*)Cout)[(size_t)row * N + colg]  = v;
      }
}

// ---------------- fused RoPE Q, RoPE K, pack V -> frag-interleaved layouts ---------
// Q scaled by 0.125*log2(e). Qr/Kr: d-dim permuted per 32-block; Vt: t-dim permuted.
__global__ void reorg(const ushort* __restrict__ QKV, ushort* __restrict__ Qr,
                      ushort* __restrict__ Kr, ushort* __restrict__ Vt,
                      const float* __restrict__ fc, const float* __restrict__ fs) {
  int idx = blockIdx.x * 256 + threadIdx.x;   // < 917504
  if (idx < 786432) {
    // RoPE, 4 interleaved pairs = 8 consecutive logical d per thread
    int nheads, col_off; ushort* dst; float scale; int id;
    if (idx < 524288) { id = idx * 4; nheads = NHEAD; col_off = 0; dst = Qr; scale = QSCALE_EXP2; }
    else { id = (idx - 524288) * 4; nheads = NKVH; col_off = 2048; dst = Kr; scale = 1.0f; }
    int per_t = nheads * 64;
    int t  = id / per_t;
    int r  = id - t * per_t;
    int hh = r >> 6;
    int c2 = (r >> 5) & 1;
    int j  = r & 31;                      // multiple of 4; logical d0 = 2j
    int cl = col_off + hh * 128 + c2 * 64 + 2 * j;
    uint4 raw = *(const uint4*)(QKV + (size_t)t * QKVN + cl);
    const ushort* rp = (const ushort*)&raw;
    float c4[4], s4[4];
    *(float4*)c4 = *(const float4*)(fc + t * 32 + j);
    *(float4*)s4 = *(const float4*)(fs + t * 32 + j);
    ushort outv[8];
    #pragma unroll
    for (int p = 0; p < 4; ++p) {
      float rv = bf2f(rp[2*p]), iv = bf2f(rp[2*p + 1]);
      outv[2*p]     = f2bf((rv * c4[p] - iv * s4[p]) * scale);
      outv[2*p + 1] = f2bf((rv * s4[p] + iv * c4[p]) * scale);
    }
    int d0 = 2 * j;
    int o  = d0 & 31;                     // 0,8,16,24
    int q0 = o >> 2;                      // 0,2,4,6
    int s0 = ((q0 & 3) << 3) + ((q0 >> 2) << 2);
    int s1 = (((q0+1) & 3) << 3) + (((q0+1) >> 2) << 2);
    size_t ob = ((size_t)(c2 * nheads + hh) * T_SEQ + t) * HDIM + (d0 & ~31);
    *(uint2*)(dst + ob + s0) = *(const uint2*)(outv);
    *(uint2*)(dst + ob + s1) = *(const uint2*)(outv + 4);
  } else {
    // V transpose: 8 t-consecutive elems, t-permuted within 32-blocks
    int id = (idx - 786432) * 8;           // < 1048576
    int t = id & (T_SEQ - 1);              // multiple of 8
    int rest = id >> 11;                   // kh*64 + d
    ushort outv[8];
    #pragma unroll
    for (int p = 0; p < 8; ++p) outv[p] = QKV[(size_t)(t + p) * QKVN + 3072 + rest];
    int o  = t & 31;
    int q0 = o >> 2;
    int s0 = ((q0 & 3) << 3) + ((q0 >> 2) << 2);
    int s1 = (((q0+1) & 3) << 3) + (((q0+1) >> 2) << 2);
    size_t ob = (size_t)rest * T_SEQ + (t & ~31);
    *(uint2*)(Vt + ob + s0) = *(const uint2*)(outv);
    *(uint2*)(Vt + ob + s1) = *(const uint2*)(outv + 4);
  }
}

// ---------------- flash attention: two KV tiles per iteration, joint softmax -------
// 512 blocks = (head, qb). Wave w: stream st = w>>1, q-half qh = w&1 (two 16-row
// chunks qs). Main loop processes KV tiles in PAIRS: both QK^T blocks issue
// back-to-back (2x ILP), ONE joint online-softmax covers 128 keys (one max chain,
// one rescale), then both PVs. Diagonal + odd leftover use a single-tile path.
// K/V fragments direct from L2 (frag-interleaved global). No in-loop LDS/barriers.
__global__ __launch_bounds__(256, 2) void attn_kernel(const ushort* __restrict__ Qr,
                                                      const ushort* __restrict__ Kr,
                                                      const ushort* __restrict__ Vt,
                                                      const float* __restrict__ lamp,
                                                      float* __restrict__ Yf,
                                                      float* __restrict__ part) {
  const int bx = blockIdx.x;          // 0..511
  const int h  = bx & 15;
  const int jb = bx >> 4;             // pair (jb, jb+16) sums to 32 tiles
  const int qb = (jb < 16) ? (31 - jb) : (jb - 16);
  const int kh = h >> 1;
  const int tid = threadIdx.x;
  const int lane = tid & 63;
  const int w   = tid >> 6;
  const int st  = w >> 1;             // stream 0/1
  const int qh  = w & 1;              // q-half 0/1
  const int fr  = lane & 15;
  const int fg  = (lane >> 4) * 4;
  const int g8  = (lane >> 4) * 8;

  __shared__ float ob[64 * 64];       // epilogue O2 exchange (16 KB)
  __shared__ float sb[8];

  // Q fragments for this wave's stream, two 16-q chunks (frag-interleaved global)
  bf16x8 qf[2][2];                     // [qs][ks]
  #pragma unroll
  for (int qs = 0; qs < 2; ++qs) {
    const int row = qb * 64 + qh * 32 + qs * 16 + fr;
    const ushort* qp = Qr + ((size_t)(st * NHEAD + h) * T_SEQ + row) * HDIM;
    qf[qs][0] = ldfrag128(qp + g8);
    qf[qs][1] = ldfrag128(qp + 32 + g8);
  }

  float m_[2] = {-__builtin_inff(), -__builtin_inff()};
  float l_[2] = {0.f, 0.f};
  f32x4 o_[2][4];
  #pragma unroll
  for (int qs = 0; qs < 2; ++qs)
    #pragma unroll
    for (int dn = 0; dn < 4; ++dn) o_[qs][dn] = zero4();

  // per-lane fragment base pointers (row picked by fr, 16B chunk by g8)
  const ushort* Kbase = Kr + ((size_t)(st * NKVH + kh) * T_SEQ + fr) * HDIM + g8;
  const ushort* Vbase = Vt + ((size_t)(kh * 64 + fr) * T_SEQ) + g8;

// single-tile body (R12-proven), mask optional
#define SINGLE_TILE(KT, DOMASK) do {                                          \
    const int kvb_ = (KT) * 64;                                               \
    bf16x8 kf_[4][2], vf_[4][2];                                              \
    _Pragma("unroll")                                                         \
    for (int n_ = 0; n_ < 4; ++n_) {                                          \
      const ushort* kp_ = Kbase + (size_t)(kvb_ + n_ * 16) * HDIM;            \
      kf_[n_][0] = ldfrag128(kp_);                                            \
      kf_[n_][1] = ldfrag128(kp_ + 32);                                       \
      const ushort* vp_ = Vbase + (size_t)(n_ * 16) * T_SEQ + kvb_;           \
      vf_[n_][0] = ldfrag128(vp_);                                            \
      vf_[n_][1] = ldfrag128(vp_ + 32);                                       \
    }                                                                         \
    float sv_[2][4][4];                                                       \
    __builtin_amdgcn_s_setprio(1);                                            \
    _Pragma("unroll")                                                         \
    for (int n_ = 0; n_ < 4; ++n_) {                                          \
      f32x4 a0_ = zero4(), a1_ = zero4();                                     \
      _Pragma("unroll")                                                       \
      for (int ks_ = 0; ks_ < 2; ++ks_) {                                     \
        a0_ = __builtin_amdgcn_mfma_f32_16x16x32_bf16(kf_[n_][ks_], qf[0][ks_], a0_, 0, 0, 0); \
        a1_ = __builtin_amdgcn_mfma_f32_16x16x32_bf16(kf_[n_][ks_], qf[1][ks_], a1_, 0, 0, 0); \
      }                                                                       \
      _Pragma("unroll")                                                       \
      for (int i_ = 0; i_ < 4; ++i_) { sv_[0][n_][i_] = a0_[i_]; sv_[1][n_][i_] = a1_[i_]; } \
    }                                                                         \
    __builtin_amdgcn_s_setprio(0);                                            \
    if (DOMASK) {                                                             \
      _Pragma("unroll")                                                       \
      for (int qs_ = 0; qs_ < 2; ++qs_) {                                     \
        const int qloc_ = qh*32 + qs_*16 + fr;                                \
        _Pragma("unroll")                                                     \
        for (int n_ = 0; n_ < 4; ++n_)                                        \
          _Pragma("unroll")                                                   \
          for (int i_ = 0; i_ < 4; ++i_)                                      \
            if (n_*16 + fg + i_ > qloc_) sv_[qs_][n_][i_] = -__builtin_inff();\
      }                                                                       \
    }                                                                         \
    bf16x8 pa_[2][2];                                                         \
    _Pragma("unroll")                                                         \
    for (int qs_ = 0; qs_ < 2; ++qs_) {                                       \
      float rm_ = -__builtin_inff();                                          \
      _Pragma("unroll")                                                       \
      for (int n_ = 0; n_ < 4; ++n_)                                          \
        _Pragma("unroll")                                                     \
        for (int i_ = 0; i_ < 4; ++i_) rm_ = fmaxf(rm_, sv_[qs_][n_][i_]);    \
      rm_ = fmaxf(rm_, __shfl_xor(rm_, 16));                                  \
      rm_ = fmaxf(rm_, __shfl_xor(rm_, 32));                                  \
      if (!__all(rm_ <= m_[qs_] + 8.f)) {                                     \
        float mnew_ = fmaxf(m_[qs_], rm_);                                    \
        float sc_ = __builtin_amdgcn_exp2f(m_[qs_] - mnew_);                  \
        m_[qs_] = mnew_;                                                      \
        l_[qs_] *= sc_;                                                       \
        float scs_[4];                                                        \
        _Pragma("unroll")                                                     \
        for (int i_ = 0; i_ < 4; ++i_) scs_[i_] = __shfl(sc_, fg + i_);       \
        _Pragma("unroll")                                                     \
        for (int dn_ = 0; dn_ < 4; ++dn_)                                     \
          _Pragma("unroll")                                                   \
          for (int i_ = 0; i_ < 4; ++i_) o_[qs_][dn_][i_] *= scs_[i_];        \
      }                                                                       \
      float rs_ = 0.f;                                                        \
      _Pragma("unroll")                                                       \
      for (int n_ = 0; n_ < 4; ++n_)                                          \
        _Pragma("unroll")                                                     \
        for (int i_ = 0; i_ < 4; ++i_) {                                      \
          float p_ = __builtin_amdgcn_exp2f(sv_[qs_][n_][i_] - m_[qs_]);      \
          sv_[qs_][n_][i_] = p_; rs_ += p_;                                   \
        }                                                                     \
      rs_ += __shfl_xor(rs_, 16);                                             \
      rs_ += __shfl_xor(rs_, 32);                                             \
      l_[qs_] += rs_;                                                         \
      _Pragma("unroll")                                                       \
      for (int ks_ = 0; ks_ < 2; ++ks_)                                       \
        _Pragma("unroll")                                                     \
        for (int n2_ = 0; n2_ < 2; ++n2_)                                     \
          _Pragma("unroll")                                                   \
          for (int i_ = 0; i_ < 4; ++i_)                                      \
            pa_[qs_][ks_][n2_*4 + i_] = (__bf16)sv_[qs_][2*ks_ + n2_][i_];    \
    }                                                                         \
    __builtin_amdgcn_s_setprio(1);                                            \
    _Pragma("unroll")                                                         \
    for (int ks_ = 0; ks_ < 2; ++ks_)                                         \
      _Pragma("unroll")                                                       \
      for (int dn_ = 0; dn_ < 4; ++dn_) {                                     \
        o_[0][dn_] = __builtin_amdgcn_mfma_f32_16x16x32_bf16(pa_[0][ks_], vf_[dn_][ks_], o_[0][dn_], 0, 0, 0); \
        o_[1][dn_] = __builtin_amdgcn_mfma_f32_16x16x32_bf16(pa_[1][ks_], vf_[dn_][ks_], o_[1][dn_], 0, 0, 0); \
      }                                                                       \
    __builtin_amdgcn_s_setprio(0);                                            \
  } while (0)

  const int nnd = qb;                 // non-diagonal tiles: kt in [0, qb)
  int kt = 0;
  for (; kt + 1 < nnd; kt += 2) {
    const int ka = kt * 64, kb = ka + 64;
    // issue ALL loads for both tiles up front
    bf16x8 kfA[4][2], vfA[4][2], kfB[4][2], vfB[4][2];
    #pragma unroll
    for (int n = 0; n < 4; ++n) {
      const ushort* kpA = Kbase + (size_t)(ka + n * 16) * HDIM;
      const ushort* kpB = Kbase + (size_t)(kb + n * 16) * HDIM;
      kfA[n][0] = ldfrag128(kpA);  kfA[n][1] = ldfrag128(kpA + 32);
      kfB[n][0] = ldfrag128(kpB);  kfB[n][1] = ldfrag128(kpB + 32);
      const ushort* vpA = Vbase + (size_t)(n * 16) * T_SEQ + ka;
      vfA[n][0] = ldfrag128(vpA);  vfA[n][1] = ldfrag128(vpA + 32);
      const ushort* vpB = vpA + 64;
      vfB[n][0] = ldfrag128(vpB);  vfB[n][1] = ldfrag128(vpB + 32);
    }
    // both QK^T blocks (independent)
    float svA[2][4][4], svB[2][4][4];
    __builtin_amdgcn_s_setprio(1);
    #pragma unroll
    for (int n = 0; n < 4; ++n) {
      f32x4 a0 = zero4(), a1 = zero4(), b0 = zero4(), b1 = zero4();
      #pragma unroll
      for (int ks = 0; ks < 2; ++ks) {
        a0 = __builtin_amdgcn_mfma_f32_16x16x32_bf16(kfA[n][ks], qf[0][ks], a0, 0, 0, 0);
        a1 = __builtin_amdgcn_mfma_f32_16x16x32_bf16(kfA[n][ks], qf[1][ks], a1, 0, 0, 0);
        b0 = __builtin_amdgcn_mfma_f32_16x16x32_bf16(kfB[n][ks], qf[0][ks], b0, 0, 0, 0);
        b1 = __builtin_amdgcn_mfma_f32_16x16x32_bf16(kfB[n][ks], qf[1][ks], b1, 0, 0, 0);
      }
      #pragma unroll
      for (int i = 0; i < 4; ++i) {
        svA[0][n][i] = a0[i]; svA[1][n][i] = a1[i];
        svB[0][n][i] = b0[i]; svB[1][n][i] = b1[i];
      }
    }
    __builtin_amdgcn_s_setprio(0);

    // joint online-softmax over both tiles (one max/rescale per chunk)
    bf16x8 paA[2][2], paB[2][2];
    #pragma unroll
    for (int qs = 0; qs < 2; ++qs) {
      float rm = -__builtin_inff();
      #pragma unroll
      for (int n = 0; n < 4; ++n)
        #pragma unroll
        for (int i = 0; i < 4; ++i) {
          rm = fmaxf(rm, svA[qs][n][i]);
          rm = fmaxf(rm, svB[qs][n][i]);
        }
      rm = fmaxf(rm, __shfl_xor(rm, 16));
      rm = fmaxf(rm, __shfl_xor(rm, 32));
      if (!__all(rm <= m_[qs] + 8.f)) {   // defer-max (exp2 domain, THR=8)
        float mnew = fmaxf(m_[qs], rm);
        float sc = __builtin_amdgcn_exp2f(m_[qs] - mnew);
        m_[qs] = mnew;
        l_[qs] *= sc;
        float scs[4];
        #pragma unroll
        for (int i = 0; i < 4; ++i) scs[i] = __shfl(sc, fg + i);
        #pragma unroll
        for (int dn = 0; dn < 4; ++dn)
          #pragma unroll
          for (int i = 0; i < 4; ++i) o_[qs][dn][i] *= scs[i];
      }
      float rs = 0.f;
      #pragma unroll
      for (int n = 0; n < 4; ++n)
        #pragma unroll
        for (int i = 0; i < 4; ++i) {
          float pA = __builtin_amdgcn_exp2f(svA[qs][n][i] - m_[qs]);
          float pB = __builtin_amdgcn_exp2f(svB[qs][n][i] - m_[qs]);
          svA[qs][n][i] = pA; svB[qs][n][i] = pB;
          rs += pA + pB;
        }
      rs += __shfl_xor(rs, 16);
      rs += __shfl_xor(rs, 32);
      l_[qs] += rs;
      #pragma unroll
      for (int ks = 0; ks < 2; ++ks)
        #pragma unroll
        for (int n2 = 0; n2 < 2; ++n2)
          #pragma unroll
          for (int i = 0; i < 4; ++i) {
            paA[qs][ks][n2*4 + i] = (__bf16)svA[qs][2*ks + n2][i];
            paB[qs][ks][n2*4 + i] = (__bf16)svB[qs][2*ks + n2][i];
          }
    }

    // both PVs
    __builtin_amdgcn_s_setprio(1);
    #pragma unroll
    for (int ks = 0; ks < 2; ++ks)
      #pragma unroll
      for (int dn = 0; dn < 4; ++dn) {
        o_[0][dn] = __builtin_amdgcn_mfma_f32_16x16x32_bf16(paA[0][ks], vfA[dn][ks], o_[0][dn], 0, 0, 0);
        o_[1][dn] = __builtin_amdgcn_mfma_f32_16x16x32_bf16(paA[1][ks], vfA[dn][ks], o_[1][dn], 0, 0, 0);
      }
    #pragma unroll
    for (int ks = 0; ks < 2; ++ks)
      #pragma unroll
      for (int dn = 0; dn < 4; ++dn) {
        o_[0][dn] = __builtin_amdgcn_mfma_f32_16x16x32_bf16(paB[0][ks], vfB[dn][ks], o_[0][dn], 0, 0, 0);
        o_[1][dn] = __builtin_amdgcn_mfma_f32_16x16x32_bf16(paB[1][ks], vfB[dn][ks], o_[1][dn], 0, 0, 0);
      }
    __builtin_amdgcn_s_setprio(0);
  }
  if (kt < nnd) { SINGLE_TILE(kt, 0); ++kt; }
  SINGLE_TILE(qb, 1);                 // diagonal tile (masked)
#undef SINGLE_TILE

  // epilogue: normalize; exchange stream-1 O via LDS; combine + Yf + LN partials
  float iq[2][4];
  #pragma unroll
  for (int qs = 0; qs < 2; ++qs) {
    float inv = __builtin_amdgcn_rcpf(l_[qs]);
    #pragma unroll
    for (int i = 0; i < 4; ++i) iq[qs][i] = __shfl(inv, fg + i);
  }
  __syncthreads();
  if (st == 1) {
    #pragma unroll
    for (int qs = 0; qs < 2; ++qs)
      #pragma unroll
      for (int dn = 0; dn < 4; ++dn)
        #pragma unroll
        for (int i = 0; i < 4; ++i)
          ob[(qh*32 + qs*16 + fg + i)*64 + dn*16 + fr] = o_[qs][dn][i] * iq[qs][i];
  }
  __syncthreads();
  if (st == 0) {
    const float lam = *lamp;
    float s = 0.f, s2 = 0.f;
    #pragma unroll
    for (int qs = 0; qs < 2; ++qs)
      #pragma unroll
      for (int dn = 0; dn < 4; ++dn)
        #pragma unroll
        for (int i = 0; i < 4; ++i) {
          int r64 = qh*32 + qs*16 + fg + i;
          int d   = dn*16 + fr;
          float v = o_[qs][dn][i] * iq[qs][i] - lam * ob[r64*64 + d];
          Yf[(size_t)(qb*64 + r64) * DIM + h*64 + d] = v;
          s += v; s2 += v * v;
        }
    #pragma unroll
    for (int off = 1; off <= 32; off <<= 1) {
      s  += __shfl_xor(s, off);
      s2 += __shfl_xor(s2, off);
    }
    if (lane == 0) { sb[w] = s; sb[4 + w] = s2; }   // w in {0,1}
  }
  __syncthreads();
  if (tid == 0) {
    part[bx]       = sb[0] + sb[1];
    part[512 + bx] = sb[4] + sb[5];
  }
}

// ---------------- finalize per-head stats ----------------
__global__ void stats_final(const float* __restrict__ part, float* __restrict__ stat) {
  int hh = threadIdx.x;
  if (hh < 16) {
    float S = 0.f, S2 = 0.f;
    #pragma unroll
    for (int j = 0; j < 32; ++j) { S += part[j*16 + hh]; S2 += part[512 + j*16 + hh]; }
    const float N = (float)(T_SEQ * HDIM);
    float mean = S / N;
    float var  = S2 / N - mean * mean;
    stat[hh]      = mean;
    stat[16 + hh] = rsqrtf(var + 1e-5f);
  }
}

// Yb written frag-interleaved (gemm2 expects it)
__global__ void norm_cvt(const float* __restrict__ Y, const float* __restrict__ stats,
                         ushort* __restrict__ Yb) {
  int idx = (blockIdx.x * 256 + threadIdx.x) * 4;   // < T*DIM, 4-aligned
  int col = idx & (DIM - 1);
  int h = col >> 6;
  float mean = stats[h], isd = stats[16 + h] * ONE_MINUS_LI;
  float4 v = *(const float4*)(Y + idx);
  ushort4 o4;
  o4.x = f2bf((v.x - mean) * isd);
  o4.y = f2bf((v.y - mean) * isd);
  o4.z = f2bf((v.z - mean) * isd);
  o4.w = f2bf((v.w - mean) * isd);
  int q = (col & 31) >> 2;
  int idxp = (idx & ~31) + ((q & 3) << 3) + ((q >> 2) << 2);
  *(ushort4*)(Yb + idxp) = o4;
}

// ---------------- launch ----------------
extern "C" void kernel_launch(void* const* d_in, const int* in_sizes, int n_in,
                              void* d_out, int out_size, void* d_ws, size_t ws_size,
                              hipStream_t stream) {
  const float* x   = (const float*)d_in[0];
  const float* fc  = (const float*)d_in[1];
  const float* fs  = (const float*)d_in[2];
  const float* wq  = (const float*)d_in[3];
  const float* wk  = (const float*)d_in[4];
  const float* wv  = (const float*)d_in[5];
  const float* wo  = (const float*)d_in[6];
  const float* lq1 = (const float*)d_in[7];
  const float* lk1 = (const float*)d_in[8];
  const float* lq2 = (const float*)d_in[9];
  const float* lk2 = (const float*)d_in[10];
  float* out = (float*)d_out;

  char* ws = (char*)d_ws;
  const size_t OFF_WOB  = 0;                 // 2 MB, live till end
  const size_t OFF_XB   = 2097152;           // 4 MB, dead after gemm1
  const size_t OFF_WB   = 6291456;           // 7 MB, dead after gemm1
  const size_t OFF_QKV  = 13631488;          // 14.68 MB, dead after reorg
  const size_t OFF_QR   = 28311552;          // 8 MB
  const size_t OFF_KR   = 36700160;          // 4 MB
  const size_t OFF_VT   = 40894464;          // 2 MB
  const size_t OFF_Y    = 18874368;          // 8 MB over dead QKV tail
  const size_t OFF_YB   = 42991616;          // 4 MB
  const size_t OFF_ST   = 47185920;          // stats + lam + partials

  ushort* xb   = (ushort*)(ws + OFF_XB);
  ushort* Wb   = (ushort*)(ws + OFF_WB);
  ushort* Wob  = (ushort*)(ws + OFF_WOB);
  ushort* QKVb = (ushort*)(ws + OFF_QKV);
  ushort* Qr   = (ushort*)(ws + OFF_QR);
  ushort* Kr   = (ushort*)(ws + OFF_KR);
  ushort* Vt   = (ushort*)(ws + OFF_VT);
  float*  Yf   = (float*)(ws + OFF_Y);
  ushort* Yb   = (ushort*)(ws + OFF_YB);
  float*  stat = (float*)(ws + OFF_ST);
  float*  lamp = stat + 32;
  float*  part = stat + 64;                  // 1024 floats

  cvt_all<<<6656, 256, 0, stream>>>(x, wq, wk, wv, wo, xb, Wb, Wob);
  lam_kernel<<<1, 64, 0, stream>>>(lq1, lk1, lq2, lk2, lamp);

  gemm_bt<1><<<dim3(QKVN/128, T_SEQ/128), 256, 0, stream>>>(xb, Wb, QKVb, T_SEQ, QKVN, DIM);

  reorg<<<3584, 256, 0, stream>>>(QKVb, Qr, Kr, Vt, fc, fs);

  attn_kernel<<<512, 256, 0, stream>>>(Qr, Kr, Vt, lamp, Yf, part);

  stats_final<<<1, 64, 0, stream>>>(part, stat);
  norm_cvt<<<2048, 256, 0, stream>>>(Yf, stat, Yb);

  gemm_bt<0><<<dim3(DIM/128, T_SEQ/128), 256, 0, stream>>>(Yb, Wob, out, T_SEQ, DIM, DIM);
}

// Round 20
// 120.380 us; speedup vs baseline: 1.5295x; 1.1733x over previous
//
#include <hip/hip_runtime.h>
#include <hip/hip_bf16.h>
#include <cstdint>

#define T_SEQ 2048
#define DIM   1024
#define NHEAD 16
#define NKVH  8
#define HDIM  64
#define QKVN  3584   // 2048 (q) + 1024 (k) + 512 (v)

static constexpr float LAMBDA_INIT_F = 0.3555090675909693f;
static constexpr float ONE_MINUS_LI  = 0.6444909324090307f;
static constexpr float QSCALE_EXP2   = 0.1803368801111144f;  // 0.125 * log2(e)

typedef __bf16 bf16x8 __attribute__((ext_vector_type(8)));
typedef float  f32x4  __attribute__((ext_vector_type(4)));

static __device__ __forceinline__ ushort f2bf(float f) {
  union { float f; uint32_t u; } x; x.f = f;
  uint32_t u = x.u;
  uint32_t r = (u + 0x7fffu + ((u >> 16) & 1u)) >> 16;
  return (ushort)r;
}
static __device__ __forceinline__ float bf2f(ushort u) {
  union { uint32_t u; float f; } x; x.u = ((uint32_t)u) << 16; return x.f;
}
static __device__ __forceinline__ f32x4 zero4() {
  f32x4 z = {0.f, 0.f, 0.f, 0.f}; return z;
}
// Fragment-interleaved layout (GEMM arrays): within each 32-element k-block, quad
// q (=k>>2) is stored at offset ((q&3)<<3) + ((q>>2)<<2); lane's 8 frag elements
// land contiguously at [8g..8g+7] -> one 16B load.
static __device__ __forceinline__ bf16x8 ldfrag128(const ushort* p) {
  union { bf16x8 v; uint4 u; } r;
  r.u = *(const uint4*)p;
  return r.v;
}
// async global->LDS, 16B per lane; lds dest = base + lane*16 (wave-uniform base)
static __device__ __forceinline__ void gll16(const ushort* g, ushort* l) {
  __builtin_amdgcn_global_load_lds(
      (const __attribute__((address_space(1))) uint32_t*)g,
      (__attribute__((address_space(3))) uint32_t*)l, 16, 0, 0);
}

// ---------------- fused fp32->bf16 conversion, frag-interleaved output -------------
__global__ void cvt_all(const float* __restrict__ x,  const float* __restrict__ wq,
                        const float* __restrict__ wk, const float* __restrict__ wv,
                        const float* __restrict__ wo,
                        ushort* __restrict__ xb, ushort* __restrict__ Wb,
                        ushort* __restrict__ Wob) {
  int g = (blockIdx.x * 256 + threadIdx.x) * 4;   // < 6815744, 4-aligned
  float4 v; ushort* dst; int j;
  if (g < 2097152) {
    v = *(const float4*)(x + g); dst = xb; j = g;
  } else if (g < 5767168) {
    j = g - 2097152;
    const float* src = (j < 2097152) ? (wq + j)
                     : (j < 3145728) ? (wk + (j - 2097152))
                                     : (wv + (j - 3145728));
    v = *(const float4*)src; dst = Wb;
  } else {
    j = g - 5767168;
    v = *(const float4*)(wo + j); dst = Wob;
  }
  int q = (j & 31) >> 2;                         // quad within 32-block
  int jp = (j & ~31) + ((q & 3) << 3) + ((q >> 2) << 2);
  ushort4 o4;
  o4.x = f2bf(v.x); o4.y = f2bf(v.y); o4.z = f2bf(v.z); o4.w = f2bf(v.w);
  *(ushort4*)(dst + jp) = o4;
}

__global__ void lam_kernel(const float* __restrict__ lq1, const float* __restrict__ lk1,
                           const float* __restrict__ lq2, const float* __restrict__ lk2,
                           float* __restrict__ lam) {
  int lane = threadIdx.x;  // 64 threads
  float p1 = lq1[lane] * lk1[lane];
  float p2 = lq2[lane] * lk2[lane];
  #pragma unroll
  for (int off = 32; off >= 1; off >>= 1) {
    p1 += __shfl_down(p1, off);
    p2 += __shfl_down(p2, off);
  }
  if (lane == 0) *lam = expf(p1) - expf(p2) + LAMBDA_INIT_F;
}

// ---------------- GEMM (m97 + T1 swizzle), BK=64: two K-panels per barrier pair ----
template<int BF16OUT>
__global__ __launch_bounds__(256) void gemm_bt(const ushort* __restrict__ A,
                                               const ushort* __restrict__ W,
                                               void* __restrict__ Cout,
                                               int M, int N, int K) {
  __shared__ __align__(16) ushort As[2 * 128 * 32];
  __shared__ __align__(16) ushort Ws[2 * 128 * 32];
  const int tid  = threadIdx.x;
  const int lane = tid & 63;
  const int w    = tid >> 6;
  const int wr   = w >> 1, wc = w & 1;
  const int nwg = gridDim.x * gridDim.y;
  int id  = blockIdx.x * gridDim.y + blockIdx.y;
  int sw  = (id & 7) * (nwg >> 3) + (id >> 3);
  const int bm = (sw % gridDim.y) * 128;
  const int bn = (sw / gridDim.y) * 128;
  const int fr = lane & 15;
  const int fg = (lane >> 4) * 4;
  const int g8 = (lane >> 4) * 8;

  f32x4 acc[4][4];
  #pragma unroll
  for (int m = 0; m < 4; ++m)
    #pragma unroll
    for (int n = 0; n < 4; ++n) acc[m][n] = zero4();

  const int col  = (lane & 3) * 8;
  const int row0 = w * 16 + (lane >> 2);
  const int row1 = row0 + 64;
  const ushort* ga0 = A + (size_t)(bm + row0) * K + col;
  const ushort* ga1 = A + (size_t)(bm + row1) * K + col;
  const ushort* gw0 = W + (size_t)(bn + row0) * K + col;
  const ushort* gw1 = W + (size_t)(bn + row1) * K + col;
  ushort* la0 = As + (w * 512);
  ushort* la1 = As + (w * 512) + 2048;
  ushort* la2 = As + 4096 + (w * 512);
  ushort* la3 = As + 4096 + (w * 512) + 2048;
  ushort* lw0 = Ws + (w * 512);
  ushort* lw1 = Ws + (w * 512) + 2048;
  ushort* lw2 = Ws + 4096 + (w * 512);
  ushort* lw3 = Ws + 4096 + (w * 512) + 2048;

  for (int k0 = 0; k0 < K; k0 += 64) {
    gll16(ga0 + k0,      la0);
    gll16(ga1 + k0,      la1);
    gll16(ga0 + k0 + 32, la2);
    gll16(ga1 + k0 + 32, la3);
    gll16(gw0 + k0,      lw0);
    gll16(gw1 + k0,      lw1);
    gll16(gw0 + k0 + 32, lw2);
    gll16(gw1 + k0 + 32, lw3);
    __syncthreads();
    #pragma unroll
    for (int kk = 0; kk < 2; ++kk) {
      bf16x8 af[4], bfr[4];
      #pragma unroll
      for (int m = 0; m < 4; ++m)
        af[m]  = ldfrag128(&As[kk*4096 + (wr*64 + m*16 + fr) * 32 + g8]);
      #pragma unroll
      for (int n = 0; n < 4; ++n)
        bfr[n] = ldfrag128(&Ws[kk*4096 + (wc*64 + n*16 + fr) * 32 + g8]);
      #pragma unroll
      for (int m = 0; m < 4; ++m)
        #pragma unroll
        for (int n = 0; n < 4; ++n)
          acc[m][n] = __builtin_amdgcn_mfma_f32_16x16x32_bf16(af[m], bfr[n], acc[m][n], 0, 0, 0);
    }
    __syncthreads();
  }

  #pragma unroll
  for (int m = 0; m < 4; ++m)
    #pragma unroll
    for (int n = 0; n < 4; ++n)
      #pragma unroll
      for (int i = 0; i < 4; ++i) {
        int row = bm + wr*64 + m*16 + fg + i;
        int colg = bn + wc*64 + n*16 + fr;
        float v = acc[m][n][i];
        if (BF16OUT) ((ushort*)Cout)[(size_t)row * N + colg] = f2bf(v);
        else         ((float*)Cout)[(size_t)row * N + colg]  = v;
      }
}

// ---------------- fused RoPE Q/K + pack V -> LANE-PACKED fragment blocks -----------
// Q/K: plane p; block = t16-group (t>>4); within block: [ks(2)][lane(64)][8 elems],
//   lane = (t&15) | (g<<4), lane g owns k-quads {g, g+4} of the 32-k half.
// V: plane kh; block = (t>>5)*4 + (d>>4); within: [lane(64)][8], lane=(d&15)|(g<<4),
//   lane g owns t-quads {g, g+4}. Every attn fragment load = contiguous 1KB.
__global__ void reorg(const ushort* __restrict__ QKV, ushort* __restrict__ Qr,
                      ushort* __restrict__ Kr, ushort* __restrict__ Vt,
                      const float* __restrict__ fc, const float* __restrict__ fs) {
  int idx = blockIdx.x * 256 + threadIdx.x;   // < 917504
  if (idx < 786432) {
    // RoPE, 4 interleaved pairs = 8 consecutive logical d per thread
    int nheads, col_off; ushort* dst; float scale; int id;
    if (idx < 524288) { id = idx * 4; nheads = NHEAD; col_off = 0; dst = Qr; scale = QSCALE_EXP2; }
    else { id = (idx - 524288) * 4; nheads = NKVH; col_off = 2048; dst = Kr; scale = 1.0f; }
    int per_t = nheads * 64;
    int t  = id / per_t;
    int r  = id - t * per_t;
    int hh = r >> 6;
    int c2 = (r >> 5) & 1;
    int j  = r & 31;                      // multiple of 4; logical d0 = 2j (mult of 8)
    int cl = col_off + hh * 128 + c2 * 64 + 2 * j;
    uint4 raw = *(const uint4*)(QKV + (size_t)t * QKVN + cl);
    const ushort* rp = (const ushort*)&raw;
    float c4[4], s4[4];
    *(float4*)c4 = *(const float4*)(fc + t * 32 + j);
    *(float4*)s4 = *(const float4*)(fs + t * 32 + j);
    ushort outv[8];
    #pragma unroll
    for (int p = 0; p < 4; ++p) {
      float rv = bf2f(rp[2*p]), iv = bf2f(rp[2*p + 1]);
      outv[2*p]     = f2bf((rv * c4[p] - iv * s4[p]) * scale);
      outv[2*p + 1] = f2bf((rv * s4[p] + iv * c4[p]) * scale);
    }
    int d0  = 2 * j;
    int ks  = (d0 >> 5) & 1;
    int dlo = d0 & 31;                    // 0,8,16,24
    int gb  = (dlo >> 2) & 2;             // 0,2,0,2
    int e   = (dlo & 16) >> 2;            // 0,0,4,4
    size_t base = ((size_t)(c2 * nheads + hh) * T_SEQ + (t & ~15)) * HDIM
                + ks * 512 + (t & 15) * 8;
    *(uint2*)(dst + base + gb * 128 + e)        = *(const uint2*)(outv);
    *(uint2*)(dst + base + (gb + 1) * 128 + e)  = *(const uint2*)(outv + 4);
  } else {
    // V: 8 t-consecutive elems for fixed d -> lane-packed blocks
    int id = (idx - 786432) * 8;           // < 1048576
    int t = id & (T_SEQ - 1);              // multiple of 8
    int rest = id >> 11;                   // kh*64 + d
    int kh = rest >> 6, d = rest & 63;
    ushort outv[8];
    #pragma unroll
    for (int p = 0; p < 8; ++p) outv[p] = QKV[(size_t)(t + p) * QKVN + 3072 + rest];
    int tlo = t & 31;                      // 0,8,16,24
    int gb  = (tlo >> 2) & 2;
    int e   = (tlo & 16) >> 2;
    size_t base = (size_t)kh * (64 * T_SEQ)
                + ((size_t)((t >> 5) * 4 + (d >> 4))) * 512 + (d & 15) * 8;
    *(uint2*)(Vt + base + gb * 128 + e)        = *(const uint2*)(outv);
    *(uint2*)(Vt + base + (gb + 1) * 128 + e)  = *(const uint2*)(outv + 4);
  }
}

// ---------------- flash attention: lane-packed frags (1KB coalesced loads) ---------
// 512 blocks = (head, qb). Wave w: stream st = w>>1, q-half qh = w&1 (two 16-row
// chunks qs). R12-proven loop: rotated K prefetch, setprio, exp2 softmax, defer-max.
// Every K/V/Q fragment load is base + lane*8 -> one contiguous 1KB burst.
__global__ __launch_bounds__(256) void attn_kernel(const ushort* __restrict__ Qr,
                                                   const ushort* __restrict__ Kr,
                                                   const ushort* __restrict__ Vt,
                                                   const float* __restrict__ lamp,
                                                   float* __restrict__ Yf,
                                                   float* __restrict__ part) {
  const int bx = blockIdx.x;          // 0..511
  const int h  = bx & 15;
  const int jb = bx >> 4;             // pair (jb, jb+16) sums to 32 tiles
  const int qb = (jb < 16) ? (31 - jb) : (jb - 16);
  const int kh = h >> 1;
  const int tid = threadIdx.x;
  const int lane = tid & 63;
  const int w   = tid >> 6;
  const int st  = w >> 1;             // stream 0/1
  const int qh  = w & 1;              // q-half 0/1
  const int fr  = lane & 15;
  const int fg  = (lane >> 4) * 4;

  __shared__ float ob[64 * 64];       // epilogue O2 exchange (16 KB)
  __shared__ float sb[8];

  // Q fragments (lane-packed): block = qb*4 + qh*2 + qs
  bf16x8 qf[2][2];                     // [qs][ks]
  #pragma unroll
  for (int qs = 0; qs < 2; ++qs) {
    const ushort* qp = Qr + (size_t)(st * NHEAD + h) * (T_SEQ * HDIM)
                     + (size_t)(qb * 4 + qh * 2 + qs) * 1024 + lane * 8;
    qf[qs][0] = ldfrag128(qp);
    qf[qs][1] = ldfrag128(qp + 512);
  }

  float m_[2] = {-__builtin_inff(), -__builtin_inff()};
  float l_[2] = {0.f, 0.f};
  f32x4 o_[2][4];
  #pragma unroll
  for (int qs = 0; qs < 2; ++qs)
    #pragma unroll
    for (int dn = 0; dn < 4; ++dn) o_[qs][dn] = zero4();

  const ushort* Kbase = Kr + (size_t)(st * NKVH + kh) * (T_SEQ * HDIM) + lane * 8;
  const ushort* Vbase = Vt + (size_t)kh * (64 * T_SEQ) + lane * 8;

  // K fragments (single buffer, reloaded mid-tile after QK consumes them)
  bf16x8 kf[4][2], vf[4][2];
  #pragma unroll
  for (int n = 0; n < 4; ++n) {
    const ushort* kp = Kbase + (size_t)n * 1024;
    kf[n][0] = ldfrag128(kp);
    kf[n][1] = ldfrag128(kp + 512);
  }

  for (int kt = 0; kt <= qb; ++kt) {
    // V fragments for this tile (needed only after softmax -> self-hiding)
    #pragma unroll
    for (int ks = 0; ks < 2; ++ks) {
      const ushort* vp = Vbase + (size_t)((kt * 2 + ks) * 4) * 512;
      #pragma unroll
      for (int dn = 0; dn < 4; ++dn)
        vf[dn][ks] = ldfrag128(vp + dn * 512);
    }

    // S^T: mfma(K rows, Q cols); one K frag serves both q-chunks
    float sv[2][4][4];
    __builtin_amdgcn_s_setprio(1);
    #pragma unroll
    for (int n = 0; n < 4; ++n) {
      f32x4 a0 = zero4(), a1 = zero4();
      #pragma unroll
      for (int ks = 0; ks < 2; ++ks) {
        a0 = __builtin_amdgcn_mfma_f32_16x16x32_bf16(kf[n][ks], qf[0][ks], a0, 0, 0, 0);
        a1 = __builtin_amdgcn_mfma_f32_16x16x32_bf16(kf[n][ks], qf[1][ks], a1, 0, 0, 0);
      }
      #pragma unroll
      for (int i = 0; i < 4; ++i) { sv[0][n][i] = a0[i]; sv[1][n][i] = a1[i]; }
    }
    __builtin_amdgcn_s_setprio(0);

    // kf is dead now -- reload it for tile kt+1; latency hides under softmax+PV
    if (kt < qb) {
      #pragma unroll
      for (int n = 0; n < 4; ++n) {
        const ushort* kp = Kbase + (size_t)((kt + 1) * 4 + n) * 1024;
        kf[n][0] = ldfrag128(kp);
        kf[n][1] = ldfrag128(kp + 512);
      }
    }

    if (kt == qb) {                  // causal mask on diagonal tile
      #pragma unroll
      for (int qs = 0; qs < 2; ++qs) {
        const int qloc = qh*32 + qs*16 + fr;
        #pragma unroll
        for (int n = 0; n < 4; ++n)
          #pragma unroll
          for (int i = 0; i < 4; ++i)
            if (n*16 + fg + i > qloc) sv[qs][n][i] = -__builtin_inff();
      }
    }

    bf16x8 pa[2][2];
    #pragma unroll
    for (int qs = 0; qs < 2; ++qs) {
      float rm = -__builtin_inff();
      #pragma unroll
      for (int n = 0; n < 4; ++n)
        #pragma unroll
        for (int i = 0; i < 4; ++i) rm = fmaxf(rm, sv[qs][n][i]);
      rm = fmaxf(rm, __shfl_xor(rm, 16));
      rm = fmaxf(rm, __shfl_xor(rm, 32));
      if (!__all(rm <= m_[qs] + 8.f)) {   // defer-max (exp2 domain, THR=8)
        float mnew = fmaxf(m_[qs], rm);
        float sc = __builtin_amdgcn_exp2f(m_[qs] - mnew);
        m_[qs] = mnew;
        l_[qs] *= sc;
        float scs[4];
        #pragma unroll
        for (int i = 0; i < 4; ++i) scs[i] = __shfl(sc, fg + i);
        #pragma unroll
        for (int dn = 0; dn < 4; ++dn)
          #pragma unroll
          for (int i = 0; i < 4; ++i) o_[qs][dn][i] *= scs[i];
      }
      float rs = 0.f;
      #pragma unroll
      for (int n = 0; n < 4; ++n)
        #pragma unroll
        for (int i = 0; i < 4; ++i) {
          float p = __builtin_amdgcn_exp2f(sv[qs][n][i] - m_[qs]);
          sv[qs][n][i] = p; rs += p;
        }
      rs += __shfl_xor(rs, 16);
      rs += __shfl_xor(rs, 32);
      l_[qs] += rs;
      #pragma unroll
      for (int ks = 0; ks < 2; ++ks)
        #pragma unroll
        for (int n2 = 0; n2 < 2; ++n2)
          #pragma unroll
          for (int i = 0; i < 4; ++i)
            pa[qs][ks][n2*4 + i] = (__bf16)sv[qs][2*ks + n2][i];
    }

    // O += P @ V; one V frag serves both q-chunks
    __builtin_amdgcn_s_setprio(1);
    #pragma unroll
    for (int ks = 0; ks < 2; ++ks)
      #pragma unroll
      for (int dn = 0; dn < 4; ++dn) {
        o_[0][dn] = __builtin_amdgcn_mfma_f32_16x16x32_bf16(pa[0][ks], vf[dn][ks], o_[0][dn], 0, 0, 0);
        o_[1][dn] = __builtin_amdgcn_mfma_f32_16x16x32_bf16(pa[1][ks], vf[dn][ks], o_[1][dn], 0, 0, 0);
      }
    __builtin_amdgcn_s_setprio(0);
  }

  // epilogue: normalize; exchange stream-1 O via LDS; combine + Yf + LN partials
  float iq[2][4];
  #pragma unroll
  for (int qs = 0; qs < 2; ++qs) {
    float inv = __builtin_amdgcn_rcpf(l_[qs]);
    #pragma unroll
    for (int i = 0; i < 4; ++i) iq[qs][i] = __shfl(inv, fg + i);
  }
  __syncthreads();
  if (st == 1) {
    #pragma unroll
    for (int qs = 0; qs < 2; ++qs)
      #pragma unroll
      for (int dn = 0; dn < 4; ++dn)
        #pragma unroll
        for (int i = 0; i < 4; ++i)
          ob[(qh*32 + qs*16 + fg + i)*64 + dn*16 + fr] = o_[qs][dn][i] * iq[qs][i];
  }
  __syncthreads();
  if (st == 0) {
    const float lam = *lamp;
    float s = 0.f, s2 = 0.f;
    #pragma unroll
    for (int qs = 0; qs < 2; ++qs)
      #pragma unroll
      for (int dn = 0; dn < 4; ++dn)
        #pragma unroll
        for (int i = 0; i < 4; ++i) {
          int r64 = qh*32 + qs*16 + fg + i;
          int d   = dn*16 + fr;
          float v = o_[qs][dn][i] * iq[qs][i] - lam * ob[r64*64 + d];
          Yf[(size_t)(qb*64 + r64) * DIM + h*64 + d] = v;
          s += v; s2 += v * v;
        }
    #pragma unroll
    for (int off = 1; off <= 32; off <<= 1) {
      s  += __shfl_xor(s, off);
      s2 += __shfl_xor(s2, off);
    }
    if (lane == 0) { sb[w] = s; sb[4 + w] = s2; }   // w in {0,1}
  }
  __syncthreads();
  if (tid == 0) {
    part[bx]       = sb[0] + sb[1];
    part[512 + bx] = sb[4] + sb[5];
  }
}

// ---------------- finalize per-head stats ----------------
__global__ void stats_final(const float* __restrict__ part, float* __restrict__ stat) {
  int hh = threadIdx.x;
  if (hh < 16) {
    float S = 0.f, S2 = 0.f;
    #pragma unroll
    for (int j = 0; j < 32; ++j) { S += part[j*16 + hh]; S2 += part[512 + j*16 + hh]; }
    const float N = (float)(T_SEQ * HDIM);
    float mean = S / N;
    float var  = S2 / N - mean * mean;
    stat[hh]      = mean;
    stat[16 + hh] = rsqrtf(var + 1e-5f);
  }
}

// Yb written frag-interleaved (gemm2 expects it)
__global__ void norm_cvt(const float* __restrict__ Y, const float* __restrict__ stats,
                         ushort* __restrict__ Yb) {
  int idx = (blockIdx.x * 256 + threadIdx.x) * 4;   // < T*DIM, 4-aligned
  int col = idx & (DIM - 1);
  int h = col >> 6;
  float mean = stats[h], isd = stats[16 + h] * ONE_MINUS_LI;
  float4 v = *(const float4*)(Y + idx);
  ushort4 o4;
  o4.x = f2bf((v.x - mean) * isd);
  o4.y = f2bf((v.y - mean) * isd);
  o4.z = f2bf((v.z - mean) * isd);
  o4.w = f2bf((v.w - mean) * isd);
  int q = (col & 31) >> 2;
  int idxp = (idx & ~31) + ((q & 3) << 3) + ((q >> 2) << 2);
  *(ushort4*)(Yb + idxp) = o4;
}

// ---------------- launch ----------------
extern "C" void kernel_launch(void* const* d_in, const int* in_sizes, int n_in,
                              void* d_out, int out_size, void* d_ws, size_t ws_size,
                              hipStream_t stream) {
  const float* x   = (const float*)d_in[0];
  const float* fc  = (const float*)d_in[1];
  const float* fs  = (const float*)d_in[2];
  const float* wq  = (const float*)d_in[3];
  const float* wk  = (const float*)d_in[4];
  const float* wv  = (const float*)d_in[5];
  const float* wo  = (const float*)d_in[6];
  const float* lq1 = (const float*)d_in[7];
  const float* lk1 = (const float*)d_in[8];
  const float* lq2 = (const float*)d_in[9];
  const float* lk2 = (const float*)d_in[10];
  float* out = (float*)d_out;

  char* ws = (char*)d_ws;
  const size_t OFF_WOB  = 0;                 // 2 MB, live till end
  const size_t OFF_XB   = 2097152;           // 4 MB, dead after gemm1
  const size_t OFF_WB   = 6291456;           // 7 MB, dead after gemm1
  const size_t OFF_QKV  = 13631488;          // 14.68 MB, dead after reorg
  const size_t OFF_QR   = 28311552;          // 8 MB
  const size_t OFF_KR   = 36700160;          // 4 MB
  const size_t OFF_VT   = 40894464;          // 2 MB
  const size_t OFF_Y    = 18874368;          // 8 MB over dead QKV tail
  const size_t OFF_YB   = 42991616;          // 4 MB
  const size_t OFF_ST   = 47185920;          // stats + lam + partials

  ushort* xb   = (ushort*)(ws + OFF_XB);
  ushort* Wb   = (ushort*)(ws + OFF_WB);
  ushort* Wob  = (ushort*)(ws + OFF_WOB);
  ushort* QKVb = (ushort*)(ws + OFF_QKV);
  ushort* Qr   = (ushort*)(ws + OFF_QR);
  ushort* Kr   = (ushort*)(ws + OFF_KR);
  ushort* Vt   = (ushort*)(ws + OFF_VT);
  float*  Yf   = (float*)(ws + OFF_Y);
  ushort* Yb   = (ushort*)(ws + OFF_YB);
  float*  stat = (float*)(ws + OFF_ST);
  float*  lamp = stat + 32;
  float*  part = stat + 64;                  // 1024 floats

  cvt_all<<<6656, 256, 0, stream>>>(x, wq, wk, wv, wo, xb, Wb, Wob);
  lam_kernel<<<1, 64, 0, stream>>>(lq1, lk1, lq2, lk2, lamp);

  gemm_bt<1><<<dim3(QKVN/128, T_SEQ/128), 256, 0, stream>>>(xb, Wb, QKVb, T_SEQ, QKVN, DIM);

  reorg<<<3584, 256, 0, stream>>>(QKVb, Qr, Kr, Vt, fc, fs);

  attn_kernel<<<512, 256, 0, stream>>>(Qr, Kr, Vt, lamp, Yf, part);

  stats_final<<<1, 64, 0, stream>>>(part, stat);
  norm_cvt<<<2048, 256, 0, stream>>>(Yf, stat, Yb);

  gemm_bt<0><<<dim3(DIM/128, T_SEQ/128), 256, 0, stream>>>(Yb, Wob, out, T_SEQ, DIM, DIM);
}

// Round 21
// 117.396 us; speedup vs baseline: 1.5683x; 1.0254x over previous
//
#include <hip/hip_runtime.h>
#include <hip/hip_bf16.h>
#include <cstdint>

#define T_SEQ 2048
#define DIM   1024
#define NHEAD 16
#define NKVH  8
#define HDIM  64
#define QKVN  3584   // 2048 (q) + 1024 (k) + 512 (v)

static constexpr float LAMBDA_INIT_F = 0.3555090675909693f;
static constexpr float ONE_MINUS_LI  = 0.6444909324090307f;
static constexpr float QSCALE_EXP2   = 0.1803368801111144f;  // 0.125 * log2(e)

typedef __bf16 bf16x8 __attribute__((ext_vector_type(8)));
typedef float  f32x4  __attribute__((ext_vector_type(4)));

static __device__ __forceinline__ ushort f2bf(float f) {
  union { float f; uint32_t u; } x; x.f = f;
  uint32_t u = x.u;
  uint32_t r = (u + 0x7fffu + ((u >> 16) & 1u)) >> 16;
  return (ushort)r;
}
static __device__ __forceinline__ float bf2f(ushort u) {
  union { uint32_t u; float f; } x; x.u = ((uint32_t)u) << 16; return x.f;
}
static __device__ __forceinline__ f32x4 zero4() {
  f32x4 z = {0.f, 0.f, 0.f, 0.f}; return z;
}
// Fragment-interleaved layout (GEMM arrays): within each 32-element k-block, quad
// q (=k>>2) is stored at offset ((q&3)<<3) + ((q>>2)<<2); lane's 8 frag elements
// land contiguously at [8g..8g+7] -> one 16B load.
static __device__ __forceinline__ bf16x8 ldfrag128(const ushort* p) {
  union { bf16x8 v; uint4 u; } r;
  r.u = *(const uint4*)p;
  return r.v;
}
// async global->LDS, 16B per lane; lds dest = base + lane*16 (wave-uniform base)
static __device__ __forceinline__ void gll16(const ushort* g, ushort* l) {
  __builtin_amdgcn_global_load_lds(
      (const __attribute__((address_space(1))) uint32_t*)g,
      (__attribute__((address_space(3))) uint32_t*)l, 16, 0, 0);
}

// ---------------- fused fp32->bf16 conversion, frag-interleaved output -------------
__global__ void cvt_all(const float* __restrict__ x,  const float* __restrict__ wq,
                        const float* __restrict__ wk, const float* __restrict__ wv,
                        const float* __restrict__ wo,
                        ushort* __restrict__ xb, ushort* __restrict__ Wb,
                        ushort* __restrict__ Wob) {
  int g = (blockIdx.x * 256 + threadIdx.x) * 4;   // < 6815744, 4-aligned
  float4 v; ushort* dst; int j;
  if (g < 2097152) {
    v = *(const float4*)(x + g); dst = xb; j = g;
  } else if (g < 5767168) {
    j = g - 2097152;
    const float* src = (j < 2097152) ? (wq + j)
                     : (j < 3145728) ? (wk + (j - 2097152))
                                     : (wv + (j - 3145728));
    v = *(const float4*)src; dst = Wb;
  } else {
    j = g - 5767168;
    v = *(const float4*)(wo + j); dst = Wob;
  }
  int q = (j & 31) >> 2;                         // quad within 32-block
  int jp = (j & ~31) + ((q & 3) << 3) + ((q >> 2) << 2);
  ushort4 o4;
  o4.x = f2bf(v.x); o4.y = f2bf(v.y); o4.z = f2bf(v.z); o4.w = f2bf(v.w);
  *(ushort4*)(dst + jp) = o4;
}

__global__ void lam_kernel(const float* __restrict__ lq1, const float* __restrict__ lk1,
                           const float* __restrict__ lq2, const float* __restrict__ lk2,
                           float* __restrict__ lam) {
  int lane = threadIdx.x;  // 64 threads
  float p1 = lq1[lane] * lk1[lane];
  float p2 = lq2[lane] * lk2[lane];
  #pragma unroll
  for (int off = 32; off >= 1; off >>= 1) {
    p1 += __shfl_down(p1, off);
    p2 += __shfl_down(p2, off);
  }
  if (lane == 0) *lam = expf(p1) - expf(p2) + LAMBDA_INIT_F;
}

// ---------------- GEMM (m97 + T1 swizzle), BK=64: two K-panels per barrier pair ----
template<int BF16OUT>
__global__ __launch_bounds__(256) void gemm_bt(const ushort* __restrict__ A,
                                               const ushort* __restrict__ W,
                                               void* __restrict__ Cout,
                                               int M, int N, int K) {
  __shared__ __align__(16) ushort As[2 * 128 * 32];
  __shared__ __align__(16) ushort Ws[2 * 128 * 32];
  const int tid  = threadIdx.x;
  const int lane = tid & 63;
  const int w    = tid >> 6;
  const int wr   = w >> 1, wc = w & 1;
  const int nwg = gridDim.x * gridDim.y;
  int id  = blockIdx.x * gridDim.y + blockIdx.y;
  int sw  = (id & 7) * (nwg >> 3) + (id >> 3);
  const int bm = (sw % gridDim.y) * 128;
  const int bn = (sw / gridDim.y) * 128;
  const int fr = lane & 15;
  const int fg = (lane >> 4) * 4;
  const int g8 = (lane >> 4) * 8;

  f32x4 acc[4][4];
  #pragma unroll
  for (int m = 0; m < 4; ++m)
    #pragma unroll
    for (int n = 0; n < 4; ++n) acc[m][n] = zero4();

  const int col  = (lane & 3) * 8;
  const int row0 = w * 16 + (lane >> 2);
  const int row1 = row0 + 64;
  const ushort* ga0 = A + (size_t)(bm + row0) * K + col;
  const ushort* ga1 = A + (size_t)(bm + row1) * K + col;
  const ushort* gw0 = W + (size_t)(bn + row0) * K + col;
  const ushort* gw1 = W + (size_t)(bn + row1) * K + col;
  ushort* la0 = As + (w * 512);
  ushort* la1 = As + (w * 512) + 2048;
  ushort* la2 = As + 4096 + (w * 512);
  ushort* la3 = As + 4096 + (w * 512) + 2048;
  ushort* lw0 = Ws + (w * 512);
  ushort* lw1 = Ws + (w * 512) + 2048;
  ushort* lw2 = Ws + 4096 + (w * 512);
  ushort* lw3 = Ws + 4096 + (w * 512) + 2048;

  for (int k0 = 0; k0 < K; k0 += 64) {
    gll16(ga0 + k0,      la0);
    gll16(ga1 + k0,      la1);
    gll16(ga0 + k0 + 32, la2);
    gll16(ga1 + k0 + 32, la3);
    gll16(gw0 + k0,      lw0);
    gll16(gw1 + k0,      lw1);
    gll16(gw0 + k0 + 32, lw2);
    gll16(gw1 + k0 + 32, lw3);
    __syncthreads();
    #pragma unroll
    for (int kk = 0; kk < 2; ++kk) {
      bf16x8 af[4], bfr[4];
      #pragma unroll
      for (int m = 0; m < 4; ++m)
        af[m]  = ldfrag128(&As[kk*4096 + (wr*64 + m*16 + fr) * 32 + g8]);
      #pragma unroll
      for (int n = 0; n < 4; ++n)
        bfr[n] = ldfrag128(&Ws[kk*4096 + (wc*64 + n*16 + fr) * 32 + g8]);
      #pragma unroll
      for (int m = 0; m < 4; ++m)
        #pragma unroll
        for (int n = 0; n < 4; ++n)
          acc[m][n] = __builtin_amdgcn_mfma_f32_16x16x32_bf16(af[m], bfr[n], acc[m][n], 0, 0, 0);
    }
    __syncthreads();
  }

  #pragma unroll
  for (int m = 0; m < 4; ++m)
    #pragma unroll
    for (int n = 0; n < 4; ++n)
      #pragma unroll
      for (int i = 0; i < 4; ++i) {
        int row = bm + wr*64 + m*16 + fg + i;
        int colg = bn + wc*64 + n*16 + fr;
        float v = acc[m][n][i];
        if (BF16OUT) ((ushort*)Cout)[(size_t)row * N + colg] = f2bf(v);
        else         ((float*)Cout)[(size_t)row * N + colg]  = v;
      }
}

// ---------------- fused RoPE Q/K + pack V -> LANE-PACKED fragment blocks -----------
// Q/K: plane p; block = t16-group (t>>4); within block: [ks(2)][lane(64)][8 elems],
//   lane = (t&15) | (g<<4), lane g owns k-quads {g, g+4} of the 32-k half.
// V: plane kh; block = (t>>5)*4 + (d>>4); within: [lane(64)][8], lane=(d&15)|(g<<4),
//   lane g owns t-quads {g, g+4}. Every attn fragment load = contiguous 1KB.
__global__ void reorg(const ushort* __restrict__ QKV, ushort* __restrict__ Qr,
                      ushort* __restrict__ Kr, ushort* __restrict__ Vt,
                      const float* __restrict__ fc, const float* __restrict__ fs) {
  int idx = blockIdx.x * 256 + threadIdx.x;   // < 917504
  if (idx < 786432) {
    // RoPE, 4 interleaved pairs = 8 consecutive logical d per thread
    int nheads, col_off; ushort* dst; float scale; int id;
    if (idx < 524288) { id = idx * 4; nheads = NHEAD; col_off = 0; dst = Qr; scale = QSCALE_EXP2; }
    else { id = (idx - 524288) * 4; nheads = NKVH; col_off = 2048; dst = Kr; scale = 1.0f; }
    int per_t = nheads * 64;
    int t  = id / per_t;
    int r  = id - t * per_t;
    int hh = r >> 6;
    int c2 = (r >> 5) & 1;
    int j  = r & 31;                      // multiple of 4; logical d0 = 2j (mult of 8)
    int cl = col_off + hh * 128 + c2 * 64 + 2 * j;
    uint4 raw = *(const uint4*)(QKV + (size_t)t * QKVN + cl);
    const ushort* rp = (const ushort*)&raw;
    float c4[4], s4[4];
    *(float4*)c4 = *(const float4*)(fc + t * 32 + j);
    *(float4*)s4 = *(const float4*)(fs + t * 32 + j);
    ushort outv[8];
    #pragma unroll
    for (int p = 0; p < 4; ++p) {
      float rv = bf2f(rp[2*p]), iv = bf2f(rp[2*p + 1]);
      outv[2*p]     = f2bf((rv * c4[p] - iv * s4[p]) * scale);
      outv[2*p + 1] = f2bf((rv * s4[p] + iv * c4[p]) * scale);
    }
    int d0  = 2 * j;
    int ks  = (d0 >> 5) & 1;
    int dlo = d0 & 31;                    // 0,8,16,24
    int gb  = (dlo >> 2) & 2;             // 0,2,0,2
    int e   = (dlo & 16) >> 2;            // 0,0,4,4
    size_t base = ((size_t)(c2 * nheads + hh) * T_SEQ + (t & ~15)) * HDIM
                + ks * 512 + (t & 15) * 8;
    *(uint2*)(dst + base + gb * 128 + e)        = *(const uint2*)(outv);
    *(uint2*)(dst + base + (gb + 1) * 128 + e)  = *(const uint2*)(outv + 4);
  } else {
    // V: 8 t-consecutive elems for fixed d -> lane-packed blocks
    int id = (idx - 786432) * 8;           // < 1048576
    int t = id & (T_SEQ - 1);              // multiple of 8
    int rest = id >> 11;                   // kh*64 + d
    int kh = rest >> 6, d = rest & 63;
    ushort outv[8];
    #pragma unroll
    for (int p = 0; p < 8; ++p) outv[p] = QKV[(size_t)(t + p) * QKVN + 3072 + rest];
    int tlo = t & 31;                      // 0,8,16,24
    int gb  = (tlo >> 2) & 2;
    int e   = (tlo & 16) >> 2;
    size_t base = (size_t)kh * (64 * T_SEQ)
                + ((size_t)((t >> 5) * 4 + (d >> 4))) * 512 + (d & 15) * 8;
    *(uint2*)(Vt + base + gb * 128 + e)        = *(const uint2*)(outv);
    *(uint2*)(Vt + base + (gb + 1) * 128 + e)  = *(const uint2*)(outv + 4);
  }
}

// ---------------- flash attention: lane-packed frags + paired-tile joint softmax ---
// 512 blocks = (head, qb). Wave w: stream st = w>>1, q-half qh = w&1 (two 16-row
// chunks qs). Main loop processes KV tiles in PAIRS: both QK^T blocks issue
// back-to-back (2x MFMA ILP), ONE joint online-softmax covers 128 keys, then both
// PVs. Diagonal + odd leftover use a single-tile path. Every fragment load is
// base + lane*8 -> one contiguous 1KB burst (R20-verified lane-packed layout).
__global__ __launch_bounds__(256, 2) void attn_kernel(const ushort* __restrict__ Qr,
                                                      const ushort* __restrict__ Kr,
                                                      const ushort* __restrict__ Vt,
                                                      const float* __restrict__ lamp,
                                                      float* __restrict__ Yf,
                                                      float* __restrict__ part) {
  const int bx = blockIdx.x;          // 0..511
  const int h  = bx & 15;
  const int jb = bx >> 4;             // pair (jb, jb+16) sums to 32 tiles
  const int qb = (jb < 16) ? (31 - jb) : (jb - 16);
  const int kh = h >> 1;
  const int tid = threadIdx.x;
  const int lane = tid & 63;
  const int w   = tid >> 6;
  const int st  = w >> 1;             // stream 0/1
  const int qh  = w & 1;              // q-half 0/1
  const int fr  = lane & 15;
  const int fg  = (lane >> 4) * 4;

  __shared__ float ob[64 * 64];       // epilogue O2 exchange (16 KB)
  __shared__ float sb[8];

  // Q fragments (lane-packed): block = qb*4 + qh*2 + qs
  bf16x8 qf[2][2];                     // [qs][ks]
  #pragma unroll
  for (int qs = 0; qs < 2; ++qs) {
    const ushort* qp = Qr + (size_t)(st * NHEAD + h) * (T_SEQ * HDIM)
                     + (size_t)(qb * 4 + qh * 2 + qs) * 1024 + lane * 8;
    qf[qs][0] = ldfrag128(qp);
    qf[qs][1] = ldfrag128(qp + 512);
  }

  float m_[2] = {-__builtin_inff(), -__builtin_inff()};
  float l_[2] = {0.f, 0.f};
  f32x4 o_[2][4];
  #pragma unroll
  for (int qs = 0; qs < 2; ++qs)
    #pragma unroll
    for (int dn = 0; dn < 4; ++dn) o_[qs][dn] = zero4();

  const ushort* Kbase = Kr + (size_t)(st * NKVH + kh) * (T_SEQ * HDIM) + lane * 8;
  const ushort* Vbase = Vt + (size_t)kh * (64 * T_SEQ) + lane * 8;

// single-tile body (R20-proven), mask optional; lane-packed addressing
#define SINGLE_TILE(KT, DOMASK) do {                                          \
    bf16x8 kf_[4][2], vf_[4][2];                                              \
    _Pragma("unroll")                                                         \
    for (int n_ = 0; n_ < 4; ++n_) {                                          \
      const ushort* kp_ = Kbase + (size_t)((KT) * 4 + n_) * 1024;             \
      kf_[n_][0] = ldfrag128(kp_);                                            \
      kf_[n_][1] = ldfrag128(kp_ + 512);                                      \
    }                                                                         \
    _Pragma("unroll")                                                         \
    for (int ks_ = 0; ks_ < 2; ++ks_) {                                       \
      const ushort* vp_ = Vbase + (size_t)(((KT) * 2 + ks_) * 4) * 512;       \
      _Pragma("unroll")                                                       \
      for (int dn_ = 0; dn_ < 4; ++dn_)                                       \
        vf_[dn_][ks_] = ldfrag128(vp_ + dn_ * 512);                           \
    }                                                                         \
    float sv_[2][4][4];                                                       \
    __builtin_amdgcn_s_setprio(1);                                            \
    _Pragma("unroll")                                                         \
    for (int n_ = 0; n_ < 4; ++n_) {                                          \
      f32x4 a0_ = zero4(), a1_ = zero4();                                     \
      _Pragma("unroll")                                                       \
      for (int ks_ = 0; ks_ < 2; ++ks_) {                                     \
        a0_ = __builtin_amdgcn_mfma_f32_16x16x32_bf16(kf_[n_][ks_], qf[0][ks_], a0_, 0, 0, 0); \
        a1_ = __builtin_amdgcn_mfma_f32_16x16x32_bf16(kf_[n_][ks_], qf[1][ks_], a1_, 0, 0, 0); \
      }                                                                       \
      _Pragma("unroll")                                                       \
      for (int i_ = 0; i_ < 4; ++i_) { sv_[0][n_][i_] = a0_[i_]; sv_[1][n_][i_] = a1_[i_]; } \
    }                                                                         \
    __builtin_amdgcn_s_setprio(0);                                            \
    if (DOMASK) {                                                             \
      _Pragma("unroll")                                                       \
      for (int qs_ = 0; qs_ < 2; ++qs_) {                                     \
        const int qloc_ = qh*32 + qs_*16 + fr;                                \
        _Pragma("unroll")                                                     \
        for (int n_ = 0; n_ < 4; ++n_)                                        \
          _Pragma("unroll")                                                   \
          for (int i_ = 0; i_ < 4; ++i_)                                      \
            if (n_*16 + fg + i_ > qloc_) sv_[qs_][n_][i_] = -__builtin_inff();\
      }                                                                       \
    }                                                                         \
    bf16x8 pa_[2][2];                                                         \
    _Pragma("unroll")                                                         \
    for (int qs_ = 0; qs_ < 2; ++qs_) {                                       \
      float rm_ = -__builtin_inff();                                          \
      _Pragma("unroll")                                                       \
      for (int n_ = 0; n_ < 4; ++n_)                                          \
        _Pragma("unroll")                                                     \
        for (int i_ = 0; i_ < 4; ++i_) rm_ = fmaxf(rm_, sv_[qs_][n_][i_]);    \
      rm_ = fmaxf(rm_, __shfl_xor(rm_, 16));                                  \
      rm_ = fmaxf(rm_, __shfl_xor(rm_, 32));                                  \
      if (!__all(rm_ <= m_[qs_] + 8.f)) {                                     \
        float mnew_ = fmaxf(m_[qs_], rm_);                                    \
        float sc_ = __builtin_amdgcn_exp2f(m_[qs_] - mnew_);                  \
        m_[qs_] = mnew_;                                                      \
        l_[qs_] *= sc_;                                                       \
        float scs_[4];                                                        \
        _Pragma("unroll")                                                     \
        for (int i_ = 0; i_ < 4; ++i_) scs_[i_] = __shfl(sc_, fg + i_);       \
        _Pragma("unroll")                                                     \
        for (int dn_ = 0; dn_ < 4; ++dn_)                                     \
          _Pragma("unroll")                                                   \
          for (int i_ = 0; i_ < 4; ++i_) o_[qs_][dn_][i_] *= scs_[i_];        \
      }                                                                       \
      float rs_ = 0.f;                                                        \
      _Pragma("unroll")                                                       \
      for (int n_ = 0; n_ < 4; ++n_)                                          \
        _Pragma("unroll")                                                     \
        for (int i_ = 0; i_ < 4; ++i_) {                                      \
          float p_ = __builtin_amdgcn_exp2f(sv_[qs_][n_][i_] - m_[qs_]);      \
          sv_[qs_][n_][i_] = p_; rs_ += p_;                                   \
        }                                                                     \
      rs_ += __shfl_xor(rs_, 16);                                             \
      rs_ += __shfl_xor(rs_, 32);                                             \
      l_[qs_] += rs_;                                                         \
      _Pragma("unroll")                                                       \
      for (int ks_ = 0; ks_ < 2; ++ks_)                                       \
        _Pragma("unroll")                                                     \
        for (int n2_ = 0; n2_ < 2; ++n2_)                                     \
          _Pragma("unroll")                                                   \
          for (int i_ = 0; i_ < 4; ++i_)                                      \
            pa_[qs_][ks_][n2_*4 + i_] = (__bf16)sv_[qs_][2*ks_ + n2_][i_];    \
    }                                                                         \
    __builtin_amdgcn_s_setprio(1);                                            \
    _Pragma("unroll")                                                         \
    for (int ks_ = 0; ks_ < 2; ++ks_)                                         \
      _Pragma("unroll")                                                       \
      for (int dn_ = 0; dn_ < 4; ++dn_) {                                     \
        o_[0][dn_] = __builtin_amdgcn_mfma_f32_16x16x32_bf16(pa_[0][ks_], vf_[dn_][ks_], o_[0][dn_], 0, 0, 0); \
        o_[1][dn_] = __builtin_amdgcn_mfma_f32_16x16x32_bf16(pa_[1][ks_], vf_[dn_][ks_], o_[1][dn_], 0, 0, 0); \
      }                                                                       \
    __builtin_amdgcn_s_setprio(0);                                            \
  } while (0)

  const int nnd = qb;                 // non-diagonal tiles: kt in [0, qb)
  int kt = 0;
  for (; kt + 1 < nnd; kt += 2) {
    // issue ALL loads for both tiles up front (each = contiguous 1KB burst)
    bf16x8 kfA[4][2], vfA[4][2], kfB[4][2], vfB[4][2];
    #pragma unroll
    for (int n = 0; n < 4; ++n) {
      const ushort* kpA = Kbase + (size_t)(kt * 4 + n) * 1024;
      const ushort* kpB = kpA + 4096;
      kfA[n][0] = ldfrag128(kpA);  kfA[n][1] = ldfrag128(kpA + 512);
      kfB[n][0] = ldfrag128(kpB);  kfB[n][1] = ldfrag128(kpB + 512);
    }
    #pragma unroll
    for (int ks = 0; ks < 2; ++ks) {
      const ushort* vpA = Vbase + (size_t)((kt * 2 + ks) * 4) * 512;
      const ushort* vpB = vpA + 4096;
      #pragma unroll
      for (int dn = 0; dn < 4; ++dn) {
        vfA[dn][ks] = ldfrag128(vpA + dn * 512);
        vfB[dn][ks] = ldfrag128(vpB + dn * 512);
      }
    }
    // both QK^T blocks (independent)
    float svA[2][4][4], svB[2][4][4];
    __builtin_amdgcn_s_setprio(1);
    #pragma unroll
    for (int n = 0; n < 4; ++n) {
      f32x4 a0 = zero4(), a1 = zero4(), b0 = zero4(), b1 = zero4();
      #pragma unroll
      for (int ks = 0; ks < 2; ++ks) {
        a0 = __builtin_amdgcn_mfma_f32_16x16x32_bf16(kfA[n][ks], qf[0][ks], a0, 0, 0, 0);
        a1 = __builtin_amdgcn_mfma_f32_16x16x32_bf16(kfA[n][ks], qf[1][ks], a1, 0, 0, 0);
        b0 = __builtin_amdgcn_mfma_f32_16x16x32_bf16(kfB[n][ks], qf[0][ks], b0, 0, 0, 0);
        b1 = __builtin_amdgcn_mfma_f32_16x16x32_bf16(kfB[n][ks], qf[1][ks], b1, 0, 0, 0);
      }
      #pragma unroll
      for (int i = 0; i < 4; ++i) {
        svA[0][n][i] = a0[i]; svA[1][n][i] = a1[i];
        svB[0][n][i] = b0[i]; svB[1][n][i] = b1[i];
      }
    }
    __builtin_amdgcn_s_setprio(0);

    // joint online-softmax over both tiles (one max/rescale per chunk)
    bf16x8 paA[2][2], paB[2][2];
    #pragma unroll
    for (int qs = 0; qs < 2; ++qs) {
      float rm = -__builtin_inff();
      #pragma unroll
      for (int n = 0; n < 4; ++n)
        #pragma unroll
        for (int i = 0; i < 4; ++i) {
          rm = fmaxf(rm, svA[qs][n][i]);
          rm = fmaxf(rm, svB[qs][n][i]);
        }
      rm = fmaxf(rm, __shfl_xor(rm, 16));
      rm = fmaxf(rm, __shfl_xor(rm, 32));
      if (!__all(rm <= m_[qs] + 8.f)) {   // defer-max (exp2 domain, THR=8)
        float mnew = fmaxf(m_[qs], rm);
        float sc = __builtin_amdgcn_exp2f(m_[qs] - mnew);
        m_[qs] = mnew;
        l_[qs] *= sc;
        float scs[4];
        #pragma unroll
        for (int i = 0; i < 4; ++i) scs[i] = __shfl(sc, fg + i);
        #pragma unroll
        for (int dn = 0; dn < 4; ++dn)
          #pragma unroll
          for (int i = 0; i < 4; ++i) o_[qs][dn][i] *= scs[i];
      }
      float rs = 0.f;
      #pragma unroll
      for (int n = 0; n < 4; ++n)
        #pragma unroll
        for (int i = 0; i < 4; ++i) {
          float pA = __builtin_amdgcn_exp2f(svA[qs][n][i] - m_[qs]);
          float pB = __builtin_amdgcn_exp2f(svB[qs][n][i] - m_[qs]);
          svA[qs][n][i] = pA; svB[qs][n][i] = pB;
          rs += pA + pB;
        }
      rs += __shfl_xor(rs, 16);
      rs += __shfl_xor(rs, 32);
      l_[qs] += rs;
      #pragma unroll
      for (int ks = 0; ks < 2; ++ks)
        #pragma unroll
        for (int n2 = 0; n2 < 2; ++n2)
          #pragma unroll
          for (int i = 0; i < 4; ++i) {
            paA[qs][ks][n2*4 + i] = (__bf16)svA[qs][2*ks + n2][i];
            paB[qs][ks][n2*4 + i] = (__bf16)svB[qs][2*ks + n2][i];
          }
    }

    // both PVs
    __builtin_amdgcn_s_setprio(1);
    #pragma unroll
    for (int ks = 0; ks < 2; ++ks)
      #pragma unroll
      for (int dn = 0; dn < 4; ++dn) {
        o_[0][dn] = __builtin_amdgcn_mfma_f32_16x16x32_bf16(paA[0][ks], vfA[dn][ks], o_[0][dn], 0, 0, 0);
        o_[1][dn] = __builtin_amdgcn_mfma_f32_16x16x32_bf16(paA[1][ks], vfA[dn][ks], o_[1][dn], 0, 0, 0);
      }
    #pragma unroll
    for (int ks = 0; ks < 2; ++ks)
      #pragma unroll
      for (int dn = 0; dn < 4; ++dn) {
        o_[0][dn] = __builtin_amdgcn_mfma_f32_16x16x32_bf16(paB[0][ks], vfB[dn][ks], o_[0][dn], 0, 0, 0);
        o_[1][dn] = __builtin_amdgcn_mfma_f32_16x16x32_bf16(paB[1][ks], vfB[dn][ks], o_[1][dn], 0, 0, 0);
      }
    __builtin_amdgcn_s_setprio(0);
  }
  if (kt < nnd) { SINGLE_TILE(kt, 0); ++kt; }
  SINGLE_TILE(qb, 1);                 // diagonal tile (masked)
#undef SINGLE_TILE

  // epilogue: normalize; exchange stream-1 O via LDS; combine + Yf + LN partials
  float iq[2][4];
  #pragma unroll
  for (int qs = 0; qs < 2; ++qs) {
    float inv = __builtin_amdgcn_rcpf(l_[qs]);
    #pragma unroll
    for (int i = 0; i < 4; ++i) iq[qs][i] = __shfl(inv, fg + i);
  }
  __syncthreads();
  if (st == 1) {
    #pragma unroll
    for (int qs = 0; qs < 2; ++qs)
      #pragma unroll
      for (int dn = 0; dn < 4; ++dn)
        #pragma unroll
        for (int i = 0; i < 4; ++i)
          ob[(qh*32 + qs*16 + fg + i)*64 + dn*16 + fr] = o_[qs][dn][i] * iq[qs][i];
  }
  __syncthreads();
  if (st == 0) {
    const float lam = *lamp;
    float s = 0.f, s2 = 0.f;
    #pragma unroll
    for (int qs = 0; qs < 2; ++qs)
      #pragma unroll
      for (int dn = 0; dn < 4; ++dn)
        #pragma unroll
        for (int i = 0; i < 4; ++i) {
          int r64 = qh*32 + qs*16 + fg + i;
          int d   = dn*16 + fr;
          float v = o_[qs][dn][i] * iq[qs][i] - lam * ob[r64*64 + d];
          Yf[(size_t)(qb*64 + r64) * DIM + h*64 + d] = v;
          s += v; s2 += v * v;
        }
    #pragma unroll
    for (int off = 1; off <= 32; off <<= 1) {
      s  += __shfl_xor(s, off);
      s2 += __shfl_xor(s2, off);
    }
    if (lane == 0) { sb[w] = s; sb[4 + w] = s2; }   // w in {0,1}
  }
  __syncthreads();
  if (tid == 0) {
    part[bx]       = sb[0] + sb[1];
    part[512 + bx] = sb[4] + sb[5];
  }
}

// ---------------- finalize per-head stats ----------------
__global__ void stats_final(const float* __restrict__ part, float* __restrict__ stat) {
  int hh = threadIdx.x;
  if (hh < 16) {
    float S = 0.f, S2 = 0.f;
    #pragma unroll
    for (int j = 0; j < 32; ++j) { S += part[j*16 + hh]; S2 += part[512 + j*16 + hh]; }
    const float N = (float)(T_SEQ * HDIM);
    float mean = S / N;
    float var  = S2 / N - mean * mean;
    stat[hh]      = mean;
    stat[16 + hh] = rsqrtf(var + 1e-5f);
  }
}

// Yb written frag-interleaved (gemm2 expects it)
__global__ void norm_cvt(const float* __restrict__ Y, const float* __restrict__ stats,
                         ushort* __restrict__ Yb) {
  int idx = (blockIdx.x * 256 + threadIdx.x) * 4;   // < T*DIM, 4-aligned
  int col = idx & (DIM - 1);
  int h = col >> 6;
  float mean = stats[h], isd = stats[16 + h] * ONE_MINUS_LI;
  float4 v = *(const float4*)(Y + idx);
  ushort4 o4;
  o4.x = f2bf((v.x - mean) * isd);
  o4.y = f2bf((v.y - mean) * isd);
  o4.z = f2bf((v.z - mean) * isd);
  o4.w = f2bf((v.w - mean) * isd);
  int q = (col & 31) >> 2;
  int idxp = (idx & ~31) + ((q & 3) << 3) + ((q >> 2) << 2);
  *(ushort4*)(Yb + idxp) = o4;
}

// ---------------- launch ----------------
extern "C" void kernel_launch(void* const* d_in, const int* in_sizes, int n_in,
                              void* d_out, int out_size, void* d_ws, size_t ws_size,
                              hipStream_t stream) {
  const float* x   = (const float*)d_in[0];
  const float* fc  = (const float*)d_in[1];
  const float* fs  = (const float*)d_in[2];
  const float* wq  = (const float*)d_in[3];
  const float* wk  = (const float*)d_in[4];
  const float* wv  = (const float*)d_in[5];
  const float* wo  = (const float*)d_in[6];
  const float* lq1 = (const float*)d_in[7];
  const float* lk1 = (const float*)d_in[8];
  const float* lq2 = (const float*)d_in[9];
  const float* lk2 = (const float*)d_in[10];
  float* out = (float*)d_out;

  char* ws = (char*)d_ws;
  const size_t OFF_WOB  = 0;                 // 2 MB, live till end
  const size_t OFF_XB   = 2097152;           // 4 MB, dead after gemm1
  const size_t OFF_WB   = 6291456;           // 7 MB, dead after gemm1
  const size_t OFF_QKV  = 13631488;          // 14.68 MB, dead after reorg
  const size_t OFF_QR   = 28311552;          // 8 MB
  const size_t OFF_KR   = 36700160;          // 4 MB
  const size_t OFF_VT   = 40894464;          // 2 MB
  const size_t OFF_Y    = 18874368;          // 8 MB over dead QKV tail
  const size_t OFF_YB   = 42991616;          // 4 MB
  const size_t OFF_ST   = 47185920;          // stats + lam + partials

  ushort* xb   = (ushort*)(ws + OFF_XB);
  ushort* Wb   = (ushort*)(ws + OFF_WB);
  ushort* Wob  = (ushort*)(ws + OFF_WOB);
  ushort* QKVb = (ushort*)(ws + OFF_QKV);
  ushort* Qr   = (ushort*)(ws + OFF_QR);
  ushort* Kr   = (ushort*)(ws + OFF_KR);
  ushort* Vt   = (ushort*)(ws + OFF_VT);
  float*  Yf   = (float*)(ws + OFF_Y);
  ushort* Yb   = (ushort*)(ws + OFF_YB);
  float*  stat = (float*)(ws + OFF_ST);
  float*  lamp = stat + 32;
  float*  part = stat + 64;                  // 1024 floats

  cvt_all<<<6656, 256, 0, stream>>>(x, wq, wk, wv, wo, xb, Wb, Wob);
  lam_kernel<<<1, 64, 0, stream>>>(lq1, lk1, lq2, lk2, lamp);

  gemm_bt<1><<<dim3(QKVN/128, T_SEQ/128), 256, 0, stream>>>(xb, Wb, QKVb, T_SEQ, QKVN, DIM);

  reorg<<<3584, 256, 0, stream>>>(QKVb, Qr, Kr, Vt, fc, fs);

  attn_kernel<<<512, 256, 0, stream>>>(Qr, Kr, Vt, lamp, Yf, part);

  stats_final<<<1, 64, 0, stream>>>(part, stat);
  norm_cvt<<<2048, 256, 0, stream>>>(Yf, stat, Yb);

  gemm_bt<0><<<dim3(DIM/128, T_SEQ/128), 256, 0, stream>>>(Yb, Wob, out, T_SEQ, DIM, DIM);
}